// Round 16
// baseline (1013.669 us; speedup 1.0000x reference)
//
#include <hip/hip_runtime.h>

#define kB 4
#define kC 128
#define kN 4096
#define kD 32
#define kL 5
#define kCO 640
#define kL2E 1.4426950408889634f

typedef float f32x4 __attribute__((ext_vector_type(4)));
typedef short bf16x4 __attribute__((ext_vector_type(4)));
typedef short bf16x8 __attribute__((ext_vector_type(8)));
typedef unsigned u32;
typedef u32 u32x4 __attribute__((ext_vector_type(4)));
typedef unsigned short u16;

__device__ __forceinline__ float bf2f(u16 u) {
  unsigned v = ((unsigned)u) << 16;
  return __builtin_bit_cast(float, v);
}
__device__ __forceinline__ u16 f2bf(float f) {
  unsigned u = __builtin_bit_cast(unsigned, f);
  u += 0x7fffu + ((u >> 16) & 1u);
  return (u16)(u >> 16);
}
__device__ __forceinline__ void split2(float v, u16& hi, u16& lo) {
  hi = f2bf(v);
  lo = f2bf(v - bf2f(hi));
}
// raw v_exp_f32 (libm exp2f adds ~10 fixup ops without -ffast-math)
__device__ __forceinline__ float fexp2(float x) {
#if __has_builtin(__builtin_amdgcn_exp2f)
  return __builtin_amdgcn_exp2f(x);
#else
  return exp2f(x);
#endif
}
// pack pair (a,b) -> hi-word (trunc bf16s) and lo-word (trunc of residuals).
__device__ __forceinline__ void splitpair(float a, float b, u32& hw, u32& lw) {
  u32 ua = __builtin_bit_cast(u32, a), ub = __builtin_bit_cast(u32, b);
  u32 uam = ua & 0xffff0000u, ubm = ub & 0xffff0000u;
  hw = (ua >> 16) | ubm;
  float la = a - __builtin_bit_cast(float, uam);
  float lb = b - __builtin_bit_cast(float, ubm);
  lw = (__builtin_bit_cast(u32, la) >> 16) | (__builtin_bit_cast(u32, lb) & 0xffff0000u);
}
// s += A*B with split operands: ah*bh + ah*bl + al*bh (drops al*bl, ~2^-16 rel)
__device__ __forceinline__ f32x4 mfma3(bf16x8 ah, bf16x8 al, bf16x8 bh, bf16x8 bl, f32x4 c) {
  c = __builtin_amdgcn_mfma_f32_16x16x32_bf16(ah, bh, c, 0, 0, 0);
  c = __builtin_amdgcn_mfma_f32_16x16x32_bf16(ah, bl, c, 0, 0, 0);
  c = __builtin_amdgcn_mfma_f32_16x16x32_bf16(al, bh, c, 0, 0, 0);
  return c;
}

// ---------------- sentinel (ws too small): encodes ws MB into output
__global__ void sentinel_kernel(float* out, float val, int total) {
  int i = blockIdx.x * 256 + threadIdx.x;
  if (i < total) out[i] = val;
}

// ---------------- split fp32 weights -> bf16 hi/lo arenas
__global__ void cvt_split_kernel(const float* __restrict__ src, u16* __restrict__ dh,
                                 u16* __restrict__ dl, int count) {
  int i = blockIdx.x * 256 + threadIdx.x;
  if (i < count) {
    u16 h, l;
    split2(src[i], h, l);
    dh[i] = h;
    dl[i] = l;
  }
}

// ---------------- xh/xl[b][n][c] = split(h[b][c][n])   (transpose + split; setup only)
__global__ __launch_bounds__(256) void prep_kernel(
    const float* __restrict__ h, long hstride, long hoff,
    u16* __restrict__ xh, u16* __restrict__ xl) {
  __shared__ float t[32][33];
  int n0 = blockIdx.x * 32, c0 = blockIdx.y * 32, b = blockIdx.z;
  int tx = threadIdx.x & 31, ty = threadIdx.x >> 5;  // 32 x 8
#pragma unroll
  for (int i = 0; i < 4; ++i) {
    int c = c0 + ty + i * 8;
    t[ty + i * 8][tx] = h[(size_t)b * hstride + hoff + (size_t)c * kN + n0 + tx];
  }
  __syncthreads();
#pragma unroll
  for (int i = 0; i < 4; ++i) {
    int n = n0 + ty + i * 8, c = c0 + tx;
    u16 hh, ll;
    split2(t[tx][ty + i * 8], hh, ll);
    size_t idx = ((size_t)b * kN + n) * kC + c;
    xh[idx] = hh;
    xl[idx] = ll;
  }
}

// ---------------- QV GEMM: 5 waves x 2 tiles, 16 n-cols per block.
// V written in FRAGMENT-PACKED layout: Vp[b][nt=n/32][ct=c/16][lane][8 bf16],
// lane=(g<<4)|col holds V[ct*16+col][nt*32+4g..+3] (p=0) and [nt*32+16+4g..+3] (p=1).
__global__ __launch_bounds__(320) void qv_kernel(
    const u16* __restrict__ xh, const u16* __restrict__ xl,
    const u16* __restrict__ wqkh, const u16* __restrict__ wqkl,
    const u16* __restrict__ wvh, const u16* __restrict__ wvl,
    const float* __restrict__ bv,
    u16* __restrict__ Qh, u16* __restrict__ Ql,
    u16* __restrict__ Vph, u16* __restrict__ Vpl) {
  __shared__ float vt[4][2][16][17];
  int wave = threadIdx.x >> 6, lane = threadIdx.x & 63;  // wave 0..4
  int b = blockIdx.y;
  int n0 = blockIdx.x * 16;
  int col = lane & 15, g = lane >> 4;
  f32x4 acc[2] = {};
  const u16* xrh = xh + ((size_t)b * kN + n0 + col) * kC + g * 8;
  const u16* xrl = xl + ((size_t)b * kN + n0 + col) * kC + g * 8;
#pragma unroll
  for (int kk = 0; kk < 4; ++kk) {
    bf16x8 bh = *(const bf16x8*)(xrh + kk * 32);
    bf16x8 bl = *(const bf16x8*)(xrl + kk * 32);
#pragma unroll
    for (int i = 0; i < 2; ++i) {
      int ot = wave * 2 + i;
      size_t wi = (ot < 2) ? ((size_t)(ot * 16 + col) * kC) : ((size_t)((ot - 2) * 16 + col) * kC);
      const u16* wsh = (ot < 2) ? (wqkh + wi) : (wvh + wi);
      const u16* wsl = (ot < 2) ? (wqkl + wi) : (wvl + wi);
      bf16x8 ah = *(const bf16x8*)(wsh + kk * 32 + g * 8);
      bf16x8 al = *(const bf16x8*)(wsl + kk * 32 + g * 8);
      acc[i] = mfma3(ah, al, bh, bl, acc[i]);
    }
  }
  if (wave > 0) {
#pragma unroll
    for (int i = 0; i < 2; ++i) {
      int ct = wave * 2 + i - 2;
#pragma unroll
      for (int r = 0; r < 4; ++r)
        vt[wave - 1][i][4 * g + r][col] = acc[i][r] + bv[ct * 16 + 4 * g + r];
    }
  }
  __syncthreads();
  if (wave == 0) {
#pragma unroll
    for (int i = 0; i < 2; ++i) {
#pragma unroll
      for (int r = 0; r < 4; ++r) {
        int d = i * 16 + 4 * g + r;
        u16 hh, ll;
        split2(acc[i][r], hh, ll);
        size_t idx = ((size_t)b * kN + n0 + col) * kD + d;
        Qh[idx] = hh;
        Ql[idx] = ll;
      }
    }
  } else {
    int nt = n0 >> 5, p = (n0 >> 4) & 1;
#pragma unroll
    for (int i = 0; i < 2; ++i) {
      int ct = wave * 2 + i - 2;
      bf16x4 vh4, vl4;
#pragma unroll
      for (int j = 0; j < 4; ++j) {
        float v = vt[wave - 1][i][col][4 * g + j];
        u16 hh, ll;
        split2(v, hh, ll);
        vh4[j] = (short)hh;
        vl4[j] = (short)ll;
      }
      size_t base = ((((size_t)b * (kN / 32) + nt) * 8 + ct) * 64 + lane) * 8 + p * 4;
      *(bf16x4*)(Vph + base) = vh4;
      *(bf16x4*)(Vpl + base) = vl4;
    }
  }
}

// ---------------- pass1 v2: block n-32 (2 a-frags/wave), 4 waves split m; LDS merge
__global__ __launch_bounds__(256) void pass1_kernel(
    const u16* __restrict__ Qh, const u16* __restrict__ Ql,
    float* __restrict__ rm2, float* __restrict__ rinv) {
  __shared__ float mxs[4][32], sms[4][32];
  int wave = threadIdx.x >> 6, lane = threadIdx.x & 63;
  int b = blockIdx.y;
  int n0 = blockIdx.x * 32;
  int col = lane & 15, g = lane >> 4;
  const u16* qbh = Qh + (size_t)b * kN * kD;
  const u16* qbl = Ql + (size_t)b * kN * kD;
  bf16x8 ah0 = *(const bf16x8*)(qbh + (size_t)(n0 + col) * kD + g * 8);
  bf16x8 al0 = *(const bf16x8*)(qbl + (size_t)(n0 + col) * kD + g * 8);
  bf16x8 ah1 = *(const bf16x8*)(qbh + (size_t)(n0 + 16 + col) * kD + g * 8);
  bf16x8 al1 = *(const bf16x8*)(qbl + (size_t)(n0 + 16 + col) * kD + g * 8);
  float mx[8], sm[8];
#pragma unroll
  for (int r = 0; r < 8; ++r) { mx[r] = -3.0e38f; sm[r] = 0.f; }
#pragma unroll 1
  for (int m0 = wave * 16; m0 < kN; m0 += 64) {
    bf16x8 bh = *(const bf16x8*)(qbh + (size_t)(m0 + col) * kD + g * 8);
    bf16x8 bl = *(const bf16x8*)(qbl + (size_t)(m0 + col) * kD + g * 8);
    f32x4 s0 = {}, s1 = {};
    s0 = mfma3(ah0, al0, bh, bl, s0);
    s1 = mfma3(ah1, al1, bh, bl, s1);
#pragma unroll
    for (int r = 0; r < 4; ++r) {
      float nm0 = fmaxf(mx[r], s0[r]);
      sm[r] = sm[r] * fexp2((mx[r] - nm0) * kL2E) + fexp2((s0[r] - nm0) * kL2E);
      mx[r] = nm0;
      float nm1 = fmaxf(mx[r + 4], s1[r]);
      sm[r + 4] = sm[r + 4] * fexp2((mx[r + 4] - nm1) * kL2E) + fexp2((s1[r] - nm1) * kL2E);
      mx[r + 4] = nm1;
    }
  }
#pragma unroll
  for (int o = 1; o < 16; o <<= 1) {
#pragma unroll
    for (int r = 0; r < 8; ++r) {
      float Mo = __shfl_xor(mx[r], o, 64);
      float So = __shfl_xor(sm[r], o, 64);
      float nm = fmaxf(mx[r], Mo);
      sm[r] = sm[r] * fexp2((mx[r] - nm) * kL2E) + So * fexp2((Mo - nm) * kL2E);
      mx[r] = nm;
    }
  }
  if (col == 0) {
#pragma unroll
    for (int r = 0; r < 4; ++r) {
      mxs[wave][4 * g + r] = mx[r];
      sms[wave][4 * g + r] = sm[r];
      mxs[wave][16 + 4 * g + r] = mx[r + 4];
      sms[wave][16 + 4 * g + r] = sm[r + 4];
    }
  }
  __syncthreads();
  if (threadIdx.x < 32) {
    int t = threadIdx.x;
    float M = mxs[0][t], S = sms[0][t];
#pragma unroll
    for (int w = 1; w < 4; ++w) {
      float Mo = mxs[w][t], So = sms[w][t];
      float nm = fmaxf(M, Mo);
      S = S * fexp2((M - nm) * kL2E) + So * fexp2((Mo - nm) * kL2E);
      M = nm;
    }
    rm2[(size_t)b * kN + n0 + t] = M * kL2E;
    rinv[(size_t)b * kN + n0 + t] = 1.0f / S;
  }
}

// per-frag P compute + pack (trunc split; bit-identical to split2t elementwise)
#define PFRAG(S0, S1, CS, BPH, BPL)                       \
  {                                                       \
    float p[8];                                           \
    _Pragma("unroll") for (int r = 0; r < 4; ++r) {       \
      p[r] = fexp2(S0[r] * kL2E - e0[r]) * i0[r];         \
      p[r + 4] = fexp2(S1[r] * kL2E - e1[r]) * i1[r];     \
      CS += p[r] + p[r + 4];                              \
    }                                                     \
    u32x4 hw, lw;                                         \
    _Pragma("unroll") for (int k2 = 0; k2 < 4; ++k2) {    \
      u32 hh, llw;                                        \
      splitpair(p[2 * k2], p[2 * k2 + 1], hh, llw);       \
      hw[k2] = hh;                                        \
      lw[k2] = llw;                                       \
    }                                                     \
    BPH = __builtin_bit_cast(bf16x8, hw);                 \
    BPL = __builtin_bit_cast(bf16x8, lw);                 \
  }

// ---------------- pass2 v8: block m-64, 8 waves, 4 m-frags/wave, nn split 8-way.
// Each V row read by exactly ONE wave per block (V L2 traffic halved vs v7).
// No in-loop barriers; 4-phase 64KB-LDS end-combine.
__global__ __launch_bounds__(512) void pass2_kernel(
    const u16* __restrict__ Qh, const u16* __restrict__ Ql,
    const u16* __restrict__ Vph, const u16* __restrict__ Vpl,
    const float* __restrict__ rm2, const float* __restrict__ rinv,
    const u16* __restrict__ xh, const u16* __restrict__ xl,
    u16* __restrict__ yth, u16* __restrict__ ytl) {
  __shared__ f32x4 accs[8][8][64];  // 64KB, reused 4x
  __shared__ float csl[4][8][16];
  int wave = threadIdx.x >> 6, lane = threadIdx.x & 63;
  int b = blockIdx.y;
  int m0 = blockIdx.x * 64;
  int col = lane & 15, g = lane >> 4;
  const u16* qbh = Qh + (size_t)b * kN * kD;
  const u16* qbl = Ql + (size_t)b * kN * kD;
  const float* rmb = rm2 + (size_t)b * kN;
  const float* rib = rinv + (size_t)b * kN;
  bf16x8 bmh[4], bml[4];
#pragma unroll
  for (int f = 0; f < 4; ++f) {
    bmh[f] = *(const bf16x8*)(qbh + (size_t)(m0 + 16 * f + col) * kD + g * 8);
    bml[f] = *(const bf16x8*)(qbl + (size_t)(m0 + 16 * f + col) * kD + g * 8);
  }
  const u16* vbh = Vph + (size_t)b * (kN / 32) * 4096;
  const u16* vbl = Vpl + (size_t)b * (kN / 32) * 4096;
  f32x4 acc0[8] = {}, acc1[8] = {}, acc2[8] = {}, acc3[8] = {};
  float cs0 = 0.f, cs1 = 0.f, cs2 = 0.f, cs3 = 0.f;
#pragma unroll 1
  for (int nn = wave * 32; nn < kN; nn += 256) {
    bf16x8 ah0 = *(const bf16x8*)(qbh + (size_t)(nn + col) * kD + g * 8);
    bf16x8 al0 = *(const bf16x8*)(qbl + (size_t)(nn + col) * kD + g * 8);
    bf16x8 ah1 = *(const bf16x8*)(qbh + (size_t)(nn + 16 + col) * kD + g * 8);
    bf16x8 al1 = *(const bf16x8*)(qbl + (size_t)(nn + 16 + col) * kD + g * 8);
    f32x4 s00 = {}, s01 = {}, s10 = {}, s11 = {}, s20 = {}, s21 = {}, s30 = {}, s31 = {};
    s00 = mfma3(ah0, al0, bmh[0], bml[0], s00);
    s01 = mfma3(ah1, al1, bmh[0], bml[0], s01);
    s10 = mfma3(ah0, al0, bmh[1], bml[1], s10);
    s11 = mfma3(ah1, al1, bmh[1], bml[1], s11);
    s20 = mfma3(ah0, al0, bmh[2], bml[2], s20);
    s21 = mfma3(ah1, al1, bmh[2], bml[2], s21);
    s30 = mfma3(ah0, al0, bmh[3], bml[3], s30);
    s31 = mfma3(ah1, al1, bmh[3], bml[3], s31);
    float e0[4], i0[4], e1[4], i1[4];
#pragma unroll
    for (int r = 0; r < 4; ++r) {
      e0[r] = rmb[nn + 4 * g + r];
      i0[r] = rib[nn + 4 * g + r];
      e1[r] = rmb[nn + 16 + 4 * g + r];
      i1[r] = rib[nn + 16 + 4 * g + r];
    }
    bf16x8 bph0, bpl0, bph1, bpl1, bph2, bpl2, bph3, bpl3;
    PFRAG(s00, s01, cs0, bph0, bpl0)
    PFRAG(s10, s11, cs1, bph1, bpl1)
    PFRAG(s20, s21, cs2, bph2, bpl2)
    PFRAG(s30, s31, cs3, bph3, bpl3)
    size_t vtile = (size_t)(nn >> 5) * 4096;
#pragma unroll
    for (int ct = 0; ct < 8; ++ct) {
      size_t off = vtile + ((size_t)ct * 64 + lane) * 8;
      bf16x8 a8h = *(const bf16x8*)(vbh + off);
      bf16x8 a8l = *(const bf16x8*)(vbl + off);
      acc0[ct] = mfma3(a8h, a8l, bph0, bpl0, acc0[ct]);
      acc1[ct] = mfma3(a8h, a8l, bph1, bpl1, acc1[ct]);
      acc2[ct] = mfma3(a8h, a8l, bph2, bpl2, acc2[ct]);
      acc3[ct] = mfma3(a8h, a8l, bph3, bpl3, acc3[ct]);
    }
  }
  cs0 += __shfl_xor(cs0, 16, 64); cs0 += __shfl_xor(cs0, 32, 64);
  cs1 += __shfl_xor(cs1, 16, 64); cs1 += __shfl_xor(cs1, 32, 64);
  cs2 += __shfl_xor(cs2, 16, 64); cs2 += __shfl_xor(cs2, 32, 64);
  cs3 += __shfl_xor(cs3, 16, 64); cs3 += __shfl_xor(cs3, 32, 64);
  if (lane < 16) {
    csl[0][wave][lane] = cs0;
    csl[1][wave][lane] = cs1;
    csl[2][wave][lane] = cs2;
    csl[3][wave][lane] = cs3;
  }
#define PHASE(F, ACC)                                                            \
  {                                                                              \
    _Pragma("unroll") for (int ct = 0; ct < 8; ++ct)                             \
        accs[wave][ct][lane] = ACC[ct];                                          \
    __syncthreads();                                                             \
    float csum = 0.f;                                                            \
    _Pragma("unroll") for (int w = 0; w < 8; ++w) csum += csl[F][w][col];        \
    float inv = 1.0f / (1e-9f + csum);                                           \
    int row = m0 + 16 * F + col;                                                 \
    int ct = wave;                                                               \
    f32x4 a = accs[0][ct][lane];                                                 \
    _Pragma("unroll") for (int w = 1; w < 8; ++w) a += accs[w][ct][lane];        \
    const u16* xrh = xh + ((size_t)b * kN + row) * kC;                           \
    const u16* xrl = xl + ((size_t)b * kN + row) * kC;                           \
    bf16x4 xvh = *(const bf16x4*)(xrh + ct * 16 + 4 * g);                        \
    bf16x4 xvl = *(const bf16x4*)(xrl + ct * 16 + 4 * g);                        \
    _Pragma("unroll") for (int r = 0; r < 4; ++r) {                              \
      float xv = bf2f((u16)xvh[r]) + bf2f((u16)xvl[r]);                          \
      float y = xv - a[r] * inv;                                                 \
      u16 hh, ll;                                                                \
      split2(y, hh, ll);                                                         \
      size_t idx = ((size_t)b * kN + row) * kC + ct * 16 + 4 * g + r;            \
      yth[idx] = hh;                                                             \
      ytl[idx] = ll;                                                             \
    }                                                                            \
    __syncthreads();                                                             \
  }
  PHASE(0, acc0)
  PHASE(1, acc1)
  PHASE(2, acc2)
  PHASE(3, acc3)
#undef PHASE
}

// ---------------- conv GEMM: 4 waves x 2 output-tiles, 16 n-cols per block
__global__ __launch_bounds__(256) void tconv_kernel(
    const u16* __restrict__ inh, const u16* __restrict__ inl,
    const u16* __restrict__ wh, const u16* __restrict__ wl,
    const float* __restrict__ bias, float* __restrict__ u,
    long ustride, long uoff) {
  int wave = threadIdx.x >> 6, lane = threadIdx.x & 63;
  int b = blockIdx.y;
  int n0 = blockIdx.x * 16;
  int col = lane & 15, g = lane >> 4;
  f32x4 acc[2] = {};
  const u16* xrh = inh + ((size_t)b * kN + n0 + col) * kC + g * 8;
  const u16* xrl = inl + ((size_t)b * kN + n0 + col) * kC + g * 8;
#pragma unroll
  for (int kk = 0; kk < 4; ++kk) {
    bf16x8 bh = *(const bf16x8*)(xrh + kk * 32);
    bf16x8 bl = *(const bf16x8*)(xrl + kk * 32);
#pragma unroll
    for (int i = 0; i < 2; ++i) {
      int ot = wave * 2 + i;
      bf16x8 ah = *(const bf16x8*)(wh + (size_t)(ot * 16 + col) * kC + kk * 32 + g * 8);
      bf16x8 al = *(const bf16x8*)(wl + (size_t)(ot * 16 + col) * kC + kk * 32 + g * 8);
      acc[i] = mfma3(ah, al, bh, bl, acc[i]);
    }
  }
#pragma unroll
  for (int i = 0; i < 2; ++i) {
    int ot = wave * 2 + i;
#pragma unroll
    for (int r = 0; r < 4; ++r) {
      int c = ot * 16 + 4 * g + r;
      float v = acc[i][r] + (bias ? bias[c] : 0.f);
      u[(size_t)b * ustride + uoff + (size_t)c * kN + n0 + col] = v;
    }
  }
}

// ---------------- BN stats, SINGLE-PASS fp64 (no cancellation: double has 53 bits)
__global__ __launch_bounds__(256) void bn_stats_kernel(const float* __restrict__ u,
                                                       long ustride, long uoff,
                                                       float* __restrict__ stat) {
  int c = blockIdx.x;
  __shared__ double reds[4], redss[4];
  double s = 0.0, ss = 0.0;
  for (int i = threadIdx.x; i < kB * kN; i += 256) {
    int b = i >> 12, n = i & (kN - 1);
    float v = u[(size_t)b * ustride + uoff + (size_t)c * kN + n];
    s += (double)v;
    ss += (double)v * (double)v;
  }
#pragma unroll
  for (int o = 1; o < 64; o <<= 1) {
    s += __shfl_xor(s, o, 64);
    ss += __shfl_xor(ss, o, 64);
  }
  int wid = threadIdx.x >> 6, lane = threadIdx.x & 63;
  if (lane == 0) { reds[wid] = s; redss[wid] = ss; }
  __syncthreads();
  if (threadIdx.x == 0) {
    double S = reds[0] + reds[1] + reds[2] + reds[3];
    double SS = redss[0] + redss[1] + redss[2] + redss[3];
    double mean = S / (double)(kB * kN);
    double var = SS / (double)(kB * kN) - mean * mean;
    if (var < 0.0) var = 0.0;
    stat[c] = (float)mean;
    stat[kC + c] = rsqrtf((float)var + 1e-5f);
  }
}

// ---------------- fused bn_final + next-layer prep:
// y = relu(BN(u)) [+ h + e]; out = y; xh/xl = split(y + e)  (transpose via LDS)
__global__ __launch_bounds__(256) void bnprep_kernel(
    const float* __restrict__ u, long ustride, long uoff,
    const float* __restrict__ stat,
    const float* __restrict__ g, const float* __restrict__ bb,
    const float* __restrict__ h, long hstride, long hoff, int use_res,
    const float* __restrict__ xyz, const float* __restrict__ pw,
    const float* __restrict__ pb,
    float* __restrict__ out, long ostride, long ooff,
    u16* __restrict__ xh, u16* __restrict__ xl) {
  __shared__ float t[32][33];
  int n0 = blockIdx.x * 32, c0 = blockIdx.y * 32, b = blockIdx.z;
  int tx = threadIdx.x & 31, ty = threadIdx.x >> 5;  // 32 x 8
  const float* xp = xyz + ((size_t)b * kN + n0 + tx) * 3;
  float xv0 = xp[0], xv1 = xp[1], xv2 = xp[2];
#pragma unroll
  for (int i = 0; i < 4; ++i) {
    int c = c0 + ty + i * 8;
    float e = pw[c * 3 + 0] * xv0 + pw[c * 3 + 1] * xv1 + pw[c * 3 + 2] * xv2 + pb[c];
    float y = (u[(size_t)b * ustride + uoff + (size_t)c * kN + n0 + tx] - stat[c]) *
                  stat[kC + c] * g[c] + bb[c];
    y = fmaxf(y, 0.f);
    if (use_res) y += h[(size_t)b * hstride + hoff + (size_t)c * kN + n0 + tx] + e;
    out[(size_t)b * ostride + ooff + (size_t)c * kN + n0 + tx] = y;
    t[ty + i * 8][tx] = y + e;  // next layer's xa
  }
  __syncthreads();
#pragma unroll
  for (int i = 0; i < 4; ++i) {
    int n = n0 + ty + i * 8, c = c0 + tx;
    u16 hh, ll;
    split2(t[tx][ty + i * 8], hh, ll);
    size_t idx = ((size_t)b * kN + n) * kC + c;
    xh[idx] = hh;
    xl[idx] = ll;
  }
}

extern "C" void kernel_launch(void* const* d_in, const int* in_sizes, int n_in,
                              void* d_out, int out_size, void* d_ws, size_t ws_size,
                              hipStream_t stream) {
  const float* x = (const float*)d_in[0];
  const float* xyz = (const float*)d_in[1];
  const float* conv1_w = (const float*)d_in[2];
  const float* bn1_g = (const float*)d_in[3];
  const float* bn1_b = (const float*)d_in[4];
  const float* pos_w = (const float*)d_in[5];
  const float* pos_b = (const float*)d_in[6];
  const float* sa_wqk = (const float*)d_in[7];
  const float* sa_wv = (const float*)d_in[8];
  const float* sa_bv = (const float*)d_in[9];
  const float* sa_wt = (const float*)d_in[10];
  const float* sa_bt = (const float*)d_in[11];
  const float* sa_bng = (const float*)d_in[12];
  const float* sa_bnb = (const float*)d_in[13];
  float* out = (float*)d_out;
  char* ws = (char*)d_ws;
  const size_t MB = (size_t)1 << 20;

  const size_t NEED = 28 * MB;
  if (ws_size < NEED) {
    float val = 100.0f + (float)(ws_size >> 20);
    sentinel_kernel<<<dim3((out_size + 255) / 256), dim3(256), 0, stream>>>(out, val, out_size);
    return;
  }

  u16* xh = (u16*)(ws);                  // [0,4MB)
  u16* xl = (u16*)(ws + 4 * MB);         // [4,8MB)
  u16* yth = (u16*)(ws + 8 * MB);        // [8,12MB)
  u16* ytl = (u16*)(ws + 12 * MB);       // [12,16MB)
  u16* Vph = (u16*)(ws + 16 * MB);       // [16,20MB)  packed V hi
  u16* Vpl = (u16*)(ws + 20 * MB);       // [20,24MB)  packed V lo
  u16* Qh = (u16*)(ws + 24 * MB);        // [24,25MB)
  u16* Ql = (u16*)(ws + 25 * MB);        // [25,26MB)
  u16* wa = (u16*)(ws + 26 * MB);        // weight split arena [26,27MB)
  size_t woff = 0;
  u16* c1h = wa + woff; woff += 16384;
  u16* c1l = wa + woff; woff += 16384;
  u16* qkh = wa + woff; woff += 5 * 32 * 128;
  u16* qkl = wa + woff; woff += 5 * 32 * 128;
  u16* wvh = wa + woff; woff += 5 * 128 * 128;
  u16* wvl = wa + woff; woff += 5 * 128 * 128;
  u16* wth = wa + woff; woff += 5 * 128 * 128;
  u16* wtl = wa + woff; woff += 5 * 128 * 128;
  float* rm2 = (float*)(ws + 27 * MB);
  float* rinv = (float*)(ws + 27 * MB + 65536);
  float* stat = (float*)(ws + 27 * MB + 131072);

  dim3 blk(256);

  cvt_split_kernel<<<dim3(64), blk, 0, stream>>>(conv1_w, c1h, c1l, 16384);
  cvt_split_kernel<<<dim3(80), blk, 0, stream>>>(sa_wqk, qkh, qkl, 20480);
  cvt_split_kernel<<<dim3(320), blk, 0, stream>>>(sa_wv, wvh, wvl, 81920);
  cvt_split_kernel<<<dim3(320), blk, 0, stream>>>(sa_wt, wth, wtl, 81920);

  const long sbo = (long)kCO * kN;
  const long slice = (long)kC * kN;
  const long h0off = 4 * slice;  // h0 parked in layer-4 slice (dead after layer-0 reads)

  // ---- setup: conv1 + BN + relu -> h0; bnprep also emits layer-0 xa (h0 + emb)
  prep_kernel<<<dim3(kN / 32, kC / 32, kB), blk, 0, stream>>>(x, slice, 0, xh, xl);
  tconv_kernel<<<dim3(kN / 16, kB), blk, 0, stream>>>(
      xh, xl, c1h, c1l, nullptr, out, sbo, 0);
  bn_stats_kernel<<<dim3(kC), blk, 0, stream>>>(out, sbo, 0, stat);
  bnprep_kernel<<<dim3(kN / 32, kC / 32, kB), blk, 0, stream>>>(
      out, sbo, 0, stat, bn1_g, bn1_b, nullptr, 0, 0, 0, xyz, pos_w, pos_b,
      out, sbo, h0off, xh, xl);

  long hoff = h0off;
  for (int i = 0; i < kL; ++i) {
    long uoff = (long)i * slice;  // layer-i pre-BN u lives in out slice i (in-place BN)
    qv_kernel<<<dim3(kN / 16, kB), dim3(320), 0, stream>>>(
        xh, xl, qkh + (size_t)i * kD * kC, qkl + (size_t)i * kD * kC,
        wvh + (size_t)i * kC * kC, wvl + (size_t)i * kC * kC,
        sa_bv + (size_t)i * kC, Qh, Ql, Vph, Vpl);
    pass1_kernel<<<dim3(kN / 32, kB), blk, 0, stream>>>(Qh, Ql, rm2, rinv);
    pass2_kernel<<<dim3(kN / 64, kB), dim3(512), 0, stream>>>(
        Qh, Ql, Vph, Vpl, rm2, rinv, xh, xl, yth, ytl);
    tconv_kernel<<<dim3(kN / 16, kB), blk, 0, stream>>>(
        yth, ytl, wth + (size_t)i * kC * kC, wtl + (size_t)i * kC * kC,
        sa_bt + (size_t)i * kC, out, sbo, uoff);
    bn_stats_kernel<<<dim3(kC), blk, 0, stream>>>(out, sbo, uoff, stat);
    bnprep_kernel<<<dim3(kN / 32, kC / 32, kB), blk, 0, stream>>>(
        out, sbo, uoff, stat, sa_bng + (size_t)i * kC, sa_bnb + (size_t)i * kC,
        out, sbo, hoff, 1, xyz, pos_w, pos_b, out, sbo, uoff, xh, xl);
    hoff = uoff;
  }
}

// Round 17
// 900.368 us; speedup vs baseline: 1.1258x; 1.1258x over previous
//
#include <hip/hip_runtime.h>

#define kB 4
#define kC 128
#define kN 4096
#define kD 32
#define kL 5
#define kCO 640
#define kL2E 1.4426950408889634f

typedef float f32x4 __attribute__((ext_vector_type(4)));
typedef short bf16x4 __attribute__((ext_vector_type(4)));
typedef short bf16x8 __attribute__((ext_vector_type(8)));
typedef unsigned u32;
typedef u32 u32x4 __attribute__((ext_vector_type(4)));
typedef unsigned short u16;

__device__ __forceinline__ float bf2f(u16 u) {
  unsigned v = ((unsigned)u) << 16;
  return __builtin_bit_cast(float, v);
}
__device__ __forceinline__ u16 f2bf(float f) {
  unsigned u = __builtin_bit_cast(unsigned, f);
  u += 0x7fffu + ((u >> 16) & 1u);
  return (u16)(u >> 16);
}
__device__ __forceinline__ void split2(float v, u16& hi, u16& lo) {
  hi = f2bf(v);
  lo = f2bf(v - bf2f(hi));
}
// raw v_exp_f32 / v_log_f32 (libm versions add ~10 fixup ops without -ffast-math)
__device__ __forceinline__ float fexp2(float x) {
#if __has_builtin(__builtin_amdgcn_exp2f)
  return __builtin_amdgcn_exp2f(x);
#else
  return exp2f(x);
#endif
}
__device__ __forceinline__ float flog2(float x) {
#if __has_builtin(__builtin_amdgcn_logf)
  return __builtin_amdgcn_logf(x);
#else
  return log2f(x);
#endif
}
// pack pair (a,b) -> hi-word (trunc bf16s) and lo-word (trunc of residuals).
__device__ __forceinline__ void splitpair(float a, float b, u32& hw, u32& lw) {
  u32 ua = __builtin_bit_cast(u32, a), ub = __builtin_bit_cast(u32, b);
  u32 uam = ua & 0xffff0000u, ubm = ub & 0xffff0000u;
  hw = (ua >> 16) | ubm;
  float la = a - __builtin_bit_cast(float, uam);
  float lb = b - __builtin_bit_cast(float, ubm);
  lw = (__builtin_bit_cast(u32, la) >> 16) | (__builtin_bit_cast(u32, lb) & 0xffff0000u);
}
// s += A*B with split operands: ah*bh + ah*bl + al*bh (drops al*bl, ~2^-16 rel)
__device__ __forceinline__ f32x4 mfma3(bf16x8 ah, bf16x8 al, bf16x8 bh, bf16x8 bl, f32x4 c) {
  c = __builtin_amdgcn_mfma_f32_16x16x32_bf16(ah, bh, c, 0, 0, 0);
  c = __builtin_amdgcn_mfma_f32_16x16x32_bf16(ah, bl, c, 0, 0, 0);
  c = __builtin_amdgcn_mfma_f32_16x16x32_bf16(al, bh, c, 0, 0, 0);
  return c;
}

// ---------------- sentinel (ws too small): encodes ws MB into output
__global__ void sentinel_kernel(float* out, float val, int total) {
  int i = blockIdx.x * 256 + threadIdx.x;
  if (i < total) out[i] = val;
}

// ---------------- split fp32 weights -> bf16 hi/lo arenas
__global__ void cvt_split_kernel(const float* __restrict__ src, u16* __restrict__ dh,
                                 u16* __restrict__ dl, int count) {
  int i = blockIdx.x * 256 + threadIdx.x;
  if (i < count) {
    u16 h, l;
    split2(src[i], h, l);
    dh[i] = h;
    dl[i] = l;
  }
}

// ---------------- xh/xl[b][n][c] = split(h[b][c][n])   (transpose + split; setup only)
__global__ __launch_bounds__(256) void prep_kernel(
    const float* __restrict__ h, long hstride, long hoff,
    u16* __restrict__ xh, u16* __restrict__ xl) {
  __shared__ float t[32][33];
  int n0 = blockIdx.x * 32, c0 = blockIdx.y * 32, b = blockIdx.z;
  int tx = threadIdx.x & 31, ty = threadIdx.x >> 5;  // 32 x 8
#pragma unroll
  for (int i = 0; i < 4; ++i) {
    int c = c0 + ty + i * 8;
    t[ty + i * 8][tx] = h[(size_t)b * hstride + hoff + (size_t)c * kN + n0 + tx];
  }
  __syncthreads();
#pragma unroll
  for (int i = 0; i < 4; ++i) {
    int n = n0 + ty + i * 8, c = c0 + tx;
    u16 hh, ll;
    split2(t[tx][ty + i * 8], hh, ll);
    size_t idx = ((size_t)b * kN + n) * kC + c;
    xh[idx] = hh;
    xl[idx] = ll;
  }
}

// ---------------- QV GEMM: 5 waves x 2 tiles, 16 n-cols per block.
// V written in FRAGMENT-PACKED layout: Vp[b][nt=n/32][ct=c/16][lane][8 bf16],
// lane=(g<<4)|col holds V[ct*16+col][nt*32+4g..+3] (p=0) and [nt*32+16+4g..+3] (p=1).
__global__ __launch_bounds__(320) void qv_kernel(
    const u16* __restrict__ xh, const u16* __restrict__ xl,
    const u16* __restrict__ wqkh, const u16* __restrict__ wqkl,
    const u16* __restrict__ wvh, const u16* __restrict__ wvl,
    const float* __restrict__ bv,
    u16* __restrict__ Qh, u16* __restrict__ Ql,
    u16* __restrict__ Vph, u16* __restrict__ Vpl) {
  __shared__ float vt[4][2][16][17];
  int wave = threadIdx.x >> 6, lane = threadIdx.x & 63;  // wave 0..4
  int b = blockIdx.y;
  int n0 = blockIdx.x * 16;
  int col = lane & 15, g = lane >> 4;
  f32x4 acc[2] = {};
  const u16* xrh = xh + ((size_t)b * kN + n0 + col) * kC + g * 8;
  const u16* xrl = xl + ((size_t)b * kN + n0 + col) * kC + g * 8;
#pragma unroll
  for (int kk = 0; kk < 4; ++kk) {
    bf16x8 bh = *(const bf16x8*)(xrh + kk * 32);
    bf16x8 bl = *(const bf16x8*)(xrl + kk * 32);
#pragma unroll
    for (int i = 0; i < 2; ++i) {
      int ot = wave * 2 + i;
      size_t wi = (ot < 2) ? ((size_t)(ot * 16 + col) * kC) : ((size_t)((ot - 2) * 16 + col) * kC);
      const u16* wsh = (ot < 2) ? (wqkh + wi) : (wvh + wi);
      const u16* wsl = (ot < 2) ? (wqkl + wi) : (wvl + wi);
      bf16x8 ah = *(const bf16x8*)(wsh + kk * 32 + g * 8);
      bf16x8 al = *(const bf16x8*)(wsl + kk * 32 + g * 8);
      acc[i] = mfma3(ah, al, bh, bl, acc[i]);
    }
  }
  if (wave > 0) {
#pragma unroll
    for (int i = 0; i < 2; ++i) {
      int ct = wave * 2 + i - 2;
#pragma unroll
      for (int r = 0; r < 4; ++r)
        vt[wave - 1][i][4 * g + r][col] = acc[i][r] + bv[ct * 16 + 4 * g + r];
    }
  }
  __syncthreads();
  if (wave == 0) {
#pragma unroll
    for (int i = 0; i < 2; ++i) {
#pragma unroll
      for (int r = 0; r < 4; ++r) {
        int d = i * 16 + 4 * g + r;
        u16 hh, ll;
        split2(acc[i][r], hh, ll);
        size_t idx = ((size_t)b * kN + n0 + col) * kD + d;
        Qh[idx] = hh;
        Ql[idx] = ll;
      }
    }
  } else {
    int nt = n0 >> 5, p = (n0 >> 4) & 1;
#pragma unroll
    for (int i = 0; i < 2; ++i) {
      int ct = wave * 2 + i - 2;
      bf16x4 vh4, vl4;
#pragma unroll
      for (int j = 0; j < 4; ++j) {
        float v = vt[wave - 1][i][col][4 * g + j];
        u16 hh, ll;
        split2(v, hh, ll);
        vh4[j] = (short)hh;
        vl4[j] = (short)ll;
      }
      size_t base = ((((size_t)b * (kN / 32) + nt) * 8 + ct) * 64 + lane) * 8 + p * 4;
      *(bf16x4*)(Vph + base) = vh4;
      *(bf16x4*)(Vpl + base) = vl4;
    }
  }
}

// ---------------- pass1 v3: block n-32 (2 a-frags/wave), 4 waves split m; LDS merge.
// Stores e' = max*log2e + log2(rowsum): pass2's p = exp2(s*log2e - e') directly.
__global__ __launch_bounds__(256) void pass1_kernel(
    const u16* __restrict__ Qh, const u16* __restrict__ Ql,
    float* __restrict__ rme) {
  __shared__ float mxs[4][32], sms[4][32];
  int wave = threadIdx.x >> 6, lane = threadIdx.x & 63;
  int b = blockIdx.y;
  int n0 = blockIdx.x * 32;
  int col = lane & 15, g = lane >> 4;
  const u16* qbh = Qh + (size_t)b * kN * kD;
  const u16* qbl = Ql + (size_t)b * kN * kD;
  bf16x8 ah0 = *(const bf16x8*)(qbh + (size_t)(n0 + col) * kD + g * 8);
  bf16x8 al0 = *(const bf16x8*)(qbl + (size_t)(n0 + col) * kD + g * 8);
  bf16x8 ah1 = *(const bf16x8*)(qbh + (size_t)(n0 + 16 + col) * kD + g * 8);
  bf16x8 al1 = *(const bf16x8*)(qbl + (size_t)(n0 + 16 + col) * kD + g * 8);
  float mx[8], sm[8];
#pragma unroll
  for (int r = 0; r < 8; ++r) { mx[r] = -3.0e38f; sm[r] = 0.f; }
#pragma unroll 1
  for (int m0 = wave * 16; m0 < kN; m0 += 64) {
    bf16x8 bh = *(const bf16x8*)(qbh + (size_t)(m0 + col) * kD + g * 8);
    bf16x8 bl = *(const bf16x8*)(qbl + (size_t)(m0 + col) * kD + g * 8);
    f32x4 s0 = {}, s1 = {};
    s0 = mfma3(ah0, al0, bh, bl, s0);
    s1 = mfma3(ah1, al1, bh, bl, s1);
#pragma unroll
    for (int r = 0; r < 4; ++r) {
      float nm0 = fmaxf(mx[r], s0[r]);
      sm[r] = sm[r] * fexp2((mx[r] - nm0) * kL2E) + fexp2((s0[r] - nm0) * kL2E);
      mx[r] = nm0;
      float nm1 = fmaxf(mx[r + 4], s1[r]);
      sm[r + 4] = sm[r + 4] * fexp2((mx[r + 4] - nm1) * kL2E) + fexp2((s1[r] - nm1) * kL2E);
      mx[r + 4] = nm1;
    }
  }
#pragma unroll
  for (int o = 1; o < 16; o <<= 1) {
#pragma unroll
    for (int r = 0; r < 8; ++r) {
      float Mo = __shfl_xor(mx[r], o, 64);
      float So = __shfl_xor(sm[r], o, 64);
      float nm = fmaxf(mx[r], Mo);
      sm[r] = sm[r] * fexp2((mx[r] - nm) * kL2E) + So * fexp2((Mo - nm) * kL2E);
      mx[r] = nm;
    }
  }
  if (col == 0) {
#pragma unroll
    for (int r = 0; r < 4; ++r) {
      mxs[wave][4 * g + r] = mx[r];
      sms[wave][4 * g + r] = sm[r];
      mxs[wave][16 + 4 * g + r] = mx[r + 4];
      sms[wave][16 + 4 * g + r] = sm[r + 4];
    }
  }
  __syncthreads();
  if (threadIdx.x < 32) {
    int t = threadIdx.x;
    float M = mxs[0][t], S = sms[0][t];
#pragma unroll
    for (int w = 1; w < 4; ++w) {
      float Mo = mxs[w][t], So = sms[w][t];
      float nm = fmaxf(M, Mo);
      S = S * fexp2((M - nm) * kL2E) + So * fexp2((Mo - nm) * kL2E);
      M = nm;
    }
    rme[(size_t)b * kN + n0 + t] = M * kL2E + flog2(S);
  }
}

// ---------------- pass2 v9 (= proven v7 + log-folded norm): block m-32, 256 thr,
// 2 m-frags/wave (V register-reuse), p = exp2(s*log2e - e'). No in-loop barriers.
__global__ __launch_bounds__(256) void pass2_kernel(
    const u16* __restrict__ Qh, const u16* __restrict__ Ql,
    const u16* __restrict__ Vph, const u16* __restrict__ Vpl,
    const float* __restrict__ rme,
    const u16* __restrict__ xh, const u16* __restrict__ xl,
    u16* __restrict__ yth, u16* __restrict__ ytl) {
  __shared__ f32x4 accs[4][8][64];
  __shared__ float csl[2][4][16];
  int wave = threadIdx.x >> 6, lane = threadIdx.x & 63;
  int b = blockIdx.y;
  int m0 = blockIdx.x * 32;
  int col = lane & 15, g = lane >> 4;
  const u16* qbh = Qh + (size_t)b * kN * kD;
  const u16* qbl = Ql + (size_t)b * kN * kD;
  const float* rmb = rme + (size_t)b * kN;
  bf16x8 bmh0 = *(const bf16x8*)(qbh + (size_t)(m0 + col) * kD + g * 8);
  bf16x8 bml0 = *(const bf16x8*)(qbl + (size_t)(m0 + col) * kD + g * 8);
  bf16x8 bmh1 = *(const bf16x8*)(qbh + (size_t)(m0 + 16 + col) * kD + g * 8);
  bf16x8 bml1 = *(const bf16x8*)(qbl + (size_t)(m0 + 16 + col) * kD + g * 8);
  const u16* vbh = Vph + (size_t)b * (kN / 32) * 4096;
  const u16* vbl = Vpl + (size_t)b * (kN / 32) * 4096;
  f32x4 accA[8] = {}, accB[8] = {};
  float csA = 0.f, csB = 0.f;
#pragma unroll 1
  for (int nn = wave * 32; nn < kN; nn += 128) {
    bf16x8 ah0 = *(const bf16x8*)(qbh + (size_t)(nn + col) * kD + g * 8);
    bf16x8 al0 = *(const bf16x8*)(qbl + (size_t)(nn + col) * kD + g * 8);
    bf16x8 ah1 = *(const bf16x8*)(qbh + (size_t)(nn + 16 + col) * kD + g * 8);
    bf16x8 al1 = *(const bf16x8*)(qbl + (size_t)(nn + 16 + col) * kD + g * 8);
    f32x4 sA0 = {}, sA1 = {}, sB0 = {}, sB1 = {};
    sA0 = mfma3(ah0, al0, bmh0, bml0, sA0);
    sA1 = mfma3(ah1, al1, bmh0, bml0, sA1);
    sB0 = mfma3(ah0, al0, bmh1, bml1, sB0);
    sB1 = mfma3(ah1, al1, bmh1, bml1, sB1);
    float pA[8], pB[8];
#pragma unroll
    for (int r = 0; r < 4; ++r) {
      float e0 = rmb[nn + 4 * g + r];
      float e1 = rmb[nn + 16 + 4 * g + r];
      pA[r] = fexp2(sA0[r] * kL2E - e0);
      pA[r + 4] = fexp2(sA1[r] * kL2E - e1);
      pB[r] = fexp2(sB0[r] * kL2E - e0);
      pB[r + 4] = fexp2(sB1[r] * kL2E - e1);
      csA += pA[r] + pA[r + 4];
      csB += pB[r] + pB[r + 4];
    }
    u32x4 Ahw, Alw, Bhw, Blw;
#pragma unroll
    for (int k2 = 0; k2 < 4; ++k2) {
      u32 h0, l0, h1, l1;
      splitpair(pA[2 * k2], pA[2 * k2 + 1], h0, l0);
      splitpair(pB[2 * k2], pB[2 * k2 + 1], h1, l1);
      Ahw[k2] = h0; Alw[k2] = l0;
      Bhw[k2] = h1; Blw[k2] = l1;
    }
    bf16x8 bAh = __builtin_bit_cast(bf16x8, Ahw);
    bf16x8 bAl = __builtin_bit_cast(bf16x8, Alw);
    bf16x8 bBh = __builtin_bit_cast(bf16x8, Bhw);
    bf16x8 bBl = __builtin_bit_cast(bf16x8, Blw);
    size_t vtile = (size_t)(nn >> 5) * 4096;
#pragma unroll
    for (int ct = 0; ct < 8; ++ct) {
      size_t off = vtile + ((size_t)ct * 64 + lane) * 8;
      bf16x8 a8h = *(const bf16x8*)(vbh + off);
      bf16x8 a8l = *(const bf16x8*)(vbl + off);
      accA[ct] = mfma3(a8h, a8l, bAh, bAl, accA[ct]);
      accB[ct] = mfma3(a8h, a8l, bBh, bBl, accB[ct]);
    }
  }
  csA += __shfl_xor(csA, 16, 64);
  csA += __shfl_xor(csA, 32, 64);
  csB += __shfl_xor(csB, 16, 64);
  csB += __shfl_xor(csB, 32, 64);
  if (lane < 16) {
    csl[0][wave][lane] = csA;
    csl[1][wave][lane] = csB;
  }
  // ---- phase A combine + write (rows m0+col)
#pragma unroll
  for (int ct = 0; ct < 8; ++ct) accs[wave][ct][lane] = accA[ct];
  __syncthreads();
  {
    float inv = 1.0f / (1e-9f + csl[0][0][col] + csl[0][1][col] + csl[0][2][col] + csl[0][3][col]);
    const u16* xrh = xh + ((size_t)b * kN + m0 + col) * kC;
    const u16* xrl = xl + ((size_t)b * kN + m0 + col) * kC;
#pragma unroll
    for (int i = 0; i < 2; ++i) {
      int ct = wave * 2 + i;
      f32x4 a = accs[0][ct][lane];
      a += accs[1][ct][lane];
      a += accs[2][ct][lane];
      a += accs[3][ct][lane];
      bf16x4 xvh = *(const bf16x4*)(xrh + ct * 16 + 4 * g);
      bf16x4 xvl = *(const bf16x4*)(xrl + ct * 16 + 4 * g);
#pragma unroll
      for (int r = 0; r < 4; ++r) {
        float xv = bf2f((u16)xvh[r]) + bf2f((u16)xvl[r]);
        float y = xv - a[r] * inv;
        u16 hh, ll;
        split2(y, hh, ll);
        size_t idx = ((size_t)b * kN + m0 + col) * kC + ct * 16 + 4 * g + r;
        yth[idx] = hh;
        ytl[idx] = ll;
      }
    }
  }
  __syncthreads();
  // ---- phase B combine + write (rows m0+16+col)
#pragma unroll
  for (int ct = 0; ct < 8; ++ct) accs[wave][ct][lane] = accB[ct];
  __syncthreads();
  {
    float inv = 1.0f / (1e-9f + csl[1][0][col] + csl[1][1][col] + csl[1][2][col] + csl[1][3][col]);
    const u16* xrh = xh + ((size_t)b * kN + m0 + 16 + col) * kC;
    const u16* xrl = xl + ((size_t)b * kN + m0 + 16 + col) * kC;
#pragma unroll
    for (int i = 0; i < 2; ++i) {
      int ct = wave * 2 + i;
      f32x4 a = accs[0][ct][lane];
      a += accs[1][ct][lane];
      a += accs[2][ct][lane];
      a += accs[3][ct][lane];
      bf16x4 xvh = *(const bf16x4*)(xrh + ct * 16 + 4 * g);
      bf16x4 xvl = *(const bf16x4*)(xrl + ct * 16 + 4 * g);
#pragma unroll
      for (int r = 0; r < 4; ++r) {
        float xv = bf2f((u16)xvh[r]) + bf2f((u16)xvl[r]);
        float y = xv - a[r] * inv;
        u16 hh, ll;
        split2(y, hh, ll);
        size_t idx = ((size_t)b * kN + m0 + 16 + col) * kC + ct * 16 + 4 * g + r;
        yth[idx] = hh;
        ytl[idx] = ll;
      }
    }
  }
}

// ---------------- conv GEMM: 4 waves x 2 output-tiles, 16 n-cols per block
__global__ __launch_bounds__(256) void tconv_kernel(
    const u16* __restrict__ inh, const u16* __restrict__ inl,
    const u16* __restrict__ wh, const u16* __restrict__ wl,
    const float* __restrict__ bias, float* __restrict__ u,
    long ustride, long uoff) {
  int wave = threadIdx.x >> 6, lane = threadIdx.x & 63;
  int b = blockIdx.y;
  int n0 = blockIdx.x * 16;
  int col = lane & 15, g = lane >> 4;
  f32x4 acc[2] = {};
  const u16* xrh = inh + ((size_t)b * kN + n0 + col) * kC + g * 8;
  const u16* xrl = inl + ((size_t)b * kN + n0 + col) * kC + g * 8;
#pragma unroll
  for (int kk = 0; kk < 4; ++kk) {
    bf16x8 bh = *(const bf16x8*)(xrh + kk * 32);
    bf16x8 bl = *(const bf16x8*)(xrl + kk * 32);
#pragma unroll
    for (int i = 0; i < 2; ++i) {
      int ot = wave * 2 + i;
      bf16x8 ah = *(const bf16x8*)(wh + (size_t)(ot * 16 + col) * kC + kk * 32 + g * 8);
      bf16x8 al = *(const bf16x8*)(wl + (size_t)(ot * 16 + col) * kC + kk * 32 + g * 8);
      acc[i] = mfma3(ah, al, bh, bl, acc[i]);
    }
  }
#pragma unroll
  for (int i = 0; i < 2; ++i) {
    int ot = wave * 2 + i;
#pragma unroll
    for (int r = 0; r < 4; ++r) {
      int c = ot * 16 + 4 * g + r;
      float v = acc[i][r] + (bias ? bias[c] : 0.f);
      u[(size_t)b * ustride + uoff + (size_t)c * kN + n0 + col] = v;
    }
  }
}

// ---------------- BN stats, SINGLE-PASS fp64 (no cancellation: double has 53 bits)
__global__ __launch_bounds__(256) void bn_stats_kernel(const float* __restrict__ u,
                                                       long ustride, long uoff,
                                                       float* __restrict__ stat) {
  int c = blockIdx.x;
  __shared__ double reds[4], redss[4];
  double s = 0.0, ss = 0.0;
  for (int i = threadIdx.x; i < kB * kN; i += 256) {
    int b = i >> 12, n = i & (kN - 1);
    float v = u[(size_t)b * ustride + uoff + (size_t)c * kN + n];
    s += (double)v;
    ss += (double)v * (double)v;
  }
#pragma unroll
  for (int o = 1; o < 64; o <<= 1) {
    s += __shfl_xor(s, o, 64);
    ss += __shfl_xor(ss, o, 64);
  }
  int wid = threadIdx.x >> 6, lane = threadIdx.x & 63;
  if (lane == 0) { reds[wid] = s; redss[wid] = ss; }
  __syncthreads();
  if (threadIdx.x == 0) {
    double S = reds[0] + reds[1] + reds[2] + reds[3];
    double SS = redss[0] + redss[1] + redss[2] + redss[3];
    double mean = S / (double)(kB * kN);
    double var = SS / (double)(kB * kN) - mean * mean;
    if (var < 0.0) var = 0.0;
    stat[c] = (float)mean;
    stat[kC + c] = rsqrtf((float)var + 1e-5f);
  }
}

// ---------------- fused bn_final + next-layer prep:
// y = relu(BN(u)) [+ h + e]; out = y; xh/xl = split(y + e)  (transpose via LDS)
__global__ __launch_bounds__(256) void bnprep_kernel(
    const float* __restrict__ u, long ustride, long uoff,
    const float* __restrict__ stat,
    const float* __restrict__ g, const float* __restrict__ bb,
    const float* __restrict__ h, long hstride, long hoff, int use_res,
    const float* __restrict__ xyz, const float* __restrict__ pw,
    const float* __restrict__ pb,
    float* __restrict__ out, long ostride, long ooff,
    u16* __restrict__ xh, u16* __restrict__ xl) {
  __shared__ float t[32][33];
  int n0 = blockIdx.x * 32, c0 = blockIdx.y * 32, b = blockIdx.z;
  int tx = threadIdx.x & 31, ty = threadIdx.x >> 5;  // 32 x 8
  const float* xp = xyz + ((size_t)b * kN + n0 + tx) * 3;
  float xv0 = xp[0], xv1 = xp[1], xv2 = xp[2];
#pragma unroll
  for (int i = 0; i < 4; ++i) {
    int c = c0 + ty + i * 8;
    float e = pw[c * 3 + 0] * xv0 + pw[c * 3 + 1] * xv1 + pw[c * 3 + 2] * xv2 + pb[c];
    float y = (u[(size_t)b * ustride + uoff + (size_t)c * kN + n0 + tx] - stat[c]) *
                  stat[kC + c] * g[c] + bb[c];
    y = fmaxf(y, 0.f);
    if (use_res) y += h[(size_t)b * hstride + hoff + (size_t)c * kN + n0 + tx] + e;
    out[(size_t)b * ostride + ooff + (size_t)c * kN + n0 + tx] = y;
    t[ty + i * 8][tx] = y + e;  // next layer's xa
  }
  __syncthreads();
#pragma unroll
  for (int i = 0; i < 4; ++i) {
    int n = n0 + ty + i * 8, c = c0 + tx;
    u16 hh, ll;
    split2(t[tx][ty + i * 8], hh, ll);
    size_t idx = ((size_t)b * kN + n) * kC + c;
    xh[idx] = hh;
    xl[idx] = ll;
  }
}

extern "C" void kernel_launch(void* const* d_in, const int* in_sizes, int n_in,
                              void* d_out, int out_size, void* d_ws, size_t ws_size,
                              hipStream_t stream) {
  const float* x = (const float*)d_in[0];
  const float* xyz = (const float*)d_in[1];
  const float* conv1_w = (const float*)d_in[2];
  const float* bn1_g = (const float*)d_in[3];
  const float* bn1_b = (const float*)d_in[4];
  const float* pos_w = (const float*)d_in[5];
  const float* pos_b = (const float*)d_in[6];
  const float* sa_wqk = (const float*)d_in[7];
  const float* sa_wv = (const float*)d_in[8];
  const float* sa_bv = (const float*)d_in[9];
  const float* sa_wt = (const float*)d_in[10];
  const float* sa_bt = (const float*)d_in[11];
  const float* sa_bng = (const float*)d_in[12];
  const float* sa_bnb = (const float*)d_in[13];
  float* out = (float*)d_out;
  char* ws = (char*)d_ws;
  const size_t MB = (size_t)1 << 20;

  const size_t NEED = 28 * MB;
  if (ws_size < NEED) {
    float val = 100.0f + (float)(ws_size >> 20);
    sentinel_kernel<<<dim3((out_size + 255) / 256), dim3(256), 0, stream>>>(out, val, out_size);
    return;
  }

  u16* xh = (u16*)(ws);                  // [0,4MB)
  u16* xl = (u16*)(ws + 4 * MB);         // [4,8MB)
  u16* yth = (u16*)(ws + 8 * MB);        // [8,12MB)
  u16* ytl = (u16*)(ws + 12 * MB);       // [12,16MB)
  u16* Vph = (u16*)(ws + 16 * MB);       // [16,20MB)  packed V hi
  u16* Vpl = (u16*)(ws + 20 * MB);       // [20,24MB)  packed V lo
  u16* Qh = (u16*)(ws + 24 * MB);        // [24,25MB)
  u16* Ql = (u16*)(ws + 25 * MB);        // [25,26MB)
  u16* wa = (u16*)(ws + 26 * MB);        // weight split arena [26,27MB)
  size_t woff = 0;
  u16* c1h = wa + woff; woff += 16384;
  u16* c1l = wa + woff; woff += 16384;
  u16* qkh = wa + woff; woff += 5 * 32 * 128;
  u16* qkl = wa + woff; woff += 5 * 32 * 128;
  u16* wvh = wa + woff; woff += 5 * 128 * 128;
  u16* wvl = wa + woff; woff += 5 * 128 * 128;
  u16* wth = wa + woff; woff += 5 * 128 * 128;
  u16* wtl = wa + woff; woff += 5 * 128 * 128;
  float* rme = (float*)(ws + 27 * MB);
  float* stat = (float*)(ws + 27 * MB + 131072);

  dim3 blk(256);

  cvt_split_kernel<<<dim3(64), blk, 0, stream>>>(conv1_w, c1h, c1l, 16384);
  cvt_split_kernel<<<dim3(80), blk, 0, stream>>>(sa_wqk, qkh, qkl, 20480);
  cvt_split_kernel<<<dim3(320), blk, 0, stream>>>(sa_wv, wvh, wvl, 81920);
  cvt_split_kernel<<<dim3(320), blk, 0, stream>>>(sa_wt, wth, wtl, 81920);

  const long sbo = (long)kCO * kN;
  const long slice = (long)kC * kN;
  const long h0off = 4 * slice;  // h0 parked in layer-4 slice (dead after layer-0 reads)

  // ---- setup: conv1 + BN + relu -> h0; bnprep also emits layer-0 xa (h0 + emb)
  prep_kernel<<<dim3(kN / 32, kC / 32, kB), blk, 0, stream>>>(x, slice, 0, xh, xl);
  tconv_kernel<<<dim3(kN / 16, kB), blk, 0, stream>>>(
      xh, xl, c1h, c1l, nullptr, out, sbo, 0);
  bn_stats_kernel<<<dim3(kC), blk, 0, stream>>>(out, sbo, 0, stat);
  bnprep_kernel<<<dim3(kN / 32, kC / 32, kB), blk, 0, stream>>>(
      out, sbo, 0, stat, bn1_g, bn1_b, nullptr, 0, 0, 0, xyz, pos_w, pos_b,
      out, sbo, h0off, xh, xl);

  long hoff = h0off;
  for (int i = 0; i < kL; ++i) {
    long uoff = (long)i * slice;  // layer-i pre-BN u lives in out slice i (in-place BN)
    qv_kernel<<<dim3(kN / 16, kB), dim3(320), 0, stream>>>(
        xh, xl, qkh + (size_t)i * kD * kC, qkl + (size_t)i * kD * kC,
        wvh + (size_t)i * kC * kC, wvl + (size_t)i * kC * kC,
        sa_bv + (size_t)i * kC, Qh, Ql, Vph, Vpl);
    pass1_kernel<<<dim3(kN / 32, kB), blk, 0, stream>>>(Qh, Ql, rme);
    pass2_kernel<<<dim3(kN / 32, kB), blk, 0, stream>>>(
        Qh, Ql, Vph, Vpl, rme, xh, xl, yth, ytl);
    tconv_kernel<<<dim3(kN / 16, kB), blk, 0, stream>>>(
        yth, ytl, wth + (size_t)i * kC * kC, wtl + (size_t)i * kC * kC,
        sa_bt + (size_t)i * kC, out, sbo, uoff);
    bn_stats_kernel<<<dim3(kC), blk, 0, stream>>>(out, sbo, uoff, stat);
    bnprep_kernel<<<dim3(kN / 32, kC / 32, kB), blk, 0, stream>>>(
        out, sbo, uoff, stat, sa_bng + (size_t)i * kC, sa_bnb + (size_t)i * kC,
        out, sbo, hoff, 1, xyz, pos_w, pos_b, out, sbo, uoff, xh, xl);
    hoff = uoff;
  }
}

// Round 18
// 829.064 us; speedup vs baseline: 1.2227x; 1.0860x over previous
//
#include <hip/hip_runtime.h>

#define kB 4
#define kC 128
#define kN 4096
#define kD 32
#define kL 5
#define kCO 640
#define kL2E 1.4426950408889634f

typedef float f32x4 __attribute__((ext_vector_type(4)));
typedef short bf16x4 __attribute__((ext_vector_type(4)));
typedef short bf16x8 __attribute__((ext_vector_type(8)));
typedef unsigned u32;
typedef u32 u32x4 __attribute__((ext_vector_type(4)));
typedef unsigned short u16;

__device__ __forceinline__ float bf2f(u16 u) {
  unsigned v = ((unsigned)u) << 16;
  return __builtin_bit_cast(float, v);
}
__device__ __forceinline__ u16 f2bf(float f) {
  unsigned u = __builtin_bit_cast(unsigned, f);
  u += 0x7fffu + ((u >> 16) & 1u);
  return (u16)(u >> 16);
}
__device__ __forceinline__ void split2(float v, u16& hi, u16& lo) {
  hi = f2bf(v);
  lo = f2bf(v - bf2f(hi));
}
// raw v_exp_f32 / v_log_f32 (libm versions add ~10 fixup ops without -ffast-math)
__device__ __forceinline__ float fexp2(float x) {
#if __has_builtin(__builtin_amdgcn_exp2f)
  return __builtin_amdgcn_exp2f(x);
#else
  return exp2f(x);
#endif
}
__device__ __forceinline__ float flog2(float x) {
#if __has_builtin(__builtin_amdgcn_logf)
  return __builtin_amdgcn_logf(x);
#else
  return log2f(x);
#endif
}
// pack pair (a,b) -> hi-word (trunc bf16s: [bf16(a) | bf16(b)<<16]) and lo-word
// (trunc of residuals). v_perm_b32 gathers bytes [a2 a3 b2 b3] in 1 instruction.
// Bit-identical to the shift/or form.
__device__ __forceinline__ u32 pkhalves(u32 a, u32 b) {
#if __has_builtin(__builtin_amdgcn_perm)
  return __builtin_amdgcn_perm(b, a, 0x07060302u);
#else
  return (a >> 16) | (b & 0xffff0000u);
#endif
}
__device__ __forceinline__ void splitpair(float a, float b, u32& hw, u32& lw) {
  u32 ua = __builtin_bit_cast(u32, a), ub = __builtin_bit_cast(u32, b);
  hw = pkhalves(ua, ub);
  float la = a - __builtin_bit_cast(float, ua & 0xffff0000u);
  float lb = b - __builtin_bit_cast(float, ub & 0xffff0000u);
  lw = pkhalves(__builtin_bit_cast(u32, la), __builtin_bit_cast(u32, lb));
}
// s += A*B with split operands: ah*bh + ah*bl + al*bh (drops al*bl, ~2^-16 rel)
__device__ __forceinline__ f32x4 mfma3(bf16x8 ah, bf16x8 al, bf16x8 bh, bf16x8 bl, f32x4 c) {
  c = __builtin_amdgcn_mfma_f32_16x16x32_bf16(ah, bh, c, 0, 0, 0);
  c = __builtin_amdgcn_mfma_f32_16x16x32_bf16(ah, bl, c, 0, 0, 0);
  c = __builtin_amdgcn_mfma_f32_16x16x32_bf16(al, bh, c, 0, 0, 0);
  return c;
}

// ---------------- sentinel (ws too small): encodes ws MB into output
__global__ void sentinel_kernel(float* out, float val, int total) {
  int i = blockIdx.x * 256 + threadIdx.x;
  if (i < total) out[i] = val;
}

// ---------------- split fp32 weights -> bf16 hi/lo arenas
__global__ void cvt_split_kernel(const float* __restrict__ src, u16* __restrict__ dh,
                                 u16* __restrict__ dl, int count) {
  int i = blockIdx.x * 256 + threadIdx.x;
  if (i < count) {
    u16 h, l;
    split2(src[i], h, l);
    dh[i] = h;
    dl[i] = l;
  }
}

// ---------------- xh/xl[b][n][c] = split(h[b][c][n])   (transpose + split; setup only)
__global__ __launch_bounds__(256) void prep_kernel(
    const float* __restrict__ h, long hstride, long hoff,
    u16* __restrict__ xh, u16* __restrict__ xl) {
  __shared__ float t[32][33];
  int n0 = blockIdx.x * 32, c0 = blockIdx.y * 32, b = blockIdx.z;
  int tx = threadIdx.x & 31, ty = threadIdx.x >> 5;  // 32 x 8
#pragma unroll
  for (int i = 0; i < 4; ++i) {
    int c = c0 + ty + i * 8;
    t[ty + i * 8][tx] = h[(size_t)b * hstride + hoff + (size_t)c * kN + n0 + tx];
  }
  __syncthreads();
#pragma unroll
  for (int i = 0; i < 4; ++i) {
    int n = n0 + ty + i * 8, c = c0 + tx;
    u16 hh, ll;
    split2(t[tx][ty + i * 8], hh, ll);
    size_t idx = ((size_t)b * kN + n) * kC + c;
    xh[idx] = hh;
    xl[idx] = ll;
  }
}

// ---------------- QV GEMM: 5 waves x 2 tiles, 16 n-cols per block.
// V written in FRAGMENT-PACKED layout: Vp[b][nt=n/32][ct=c/16][lane][8 bf16],
// lane=(g<<4)|col holds V[ct*16+col][nt*32+4g..+3] (p=0) and [nt*32+16+4g..+3] (p=1).
__global__ __launch_bounds__(320) void qv_kernel(
    const u16* __restrict__ xh, const u16* __restrict__ xl,
    const u16* __restrict__ wqkh, const u16* __restrict__ wqkl,
    const u16* __restrict__ wvh, const u16* __restrict__ wvl,
    const float* __restrict__ bv,
    u16* __restrict__ Qh, u16* __restrict__ Ql,
    u16* __restrict__ Vph, u16* __restrict__ Vpl) {
  __shared__ float vt[4][2][16][17];
  int wave = threadIdx.x >> 6, lane = threadIdx.x & 63;  // wave 0..4
  int b = blockIdx.y;
  int n0 = blockIdx.x * 16;
  int col = lane & 15, g = lane >> 4;
  f32x4 acc[2] = {};
  const u16* xrh = xh + ((size_t)b * kN + n0 + col) * kC + g * 8;
  const u16* xrl = xl + ((size_t)b * kN + n0 + col) * kC + g * 8;
#pragma unroll
  for (int kk = 0; kk < 4; ++kk) {
    bf16x8 bh = *(const bf16x8*)(xrh + kk * 32);
    bf16x8 bl = *(const bf16x8*)(xrl + kk * 32);
#pragma unroll
    for (int i = 0; i < 2; ++i) {
      int ot = wave * 2 + i;
      size_t wi = (ot < 2) ? ((size_t)(ot * 16 + col) * kC) : ((size_t)((ot - 2) * 16 + col) * kC);
      const u16* wsh = (ot < 2) ? (wqkh + wi) : (wvh + wi);
      const u16* wsl = (ot < 2) ? (wqkl + wi) : (wvl + wi);
      bf16x8 ah = *(const bf16x8*)(wsh + kk * 32 + g * 8);
      bf16x8 al = *(const bf16x8*)(wsl + kk * 32 + g * 8);
      acc[i] = mfma3(ah, al, bh, bl, acc[i]);
    }
  }
  if (wave > 0) {
#pragma unroll
    for (int i = 0; i < 2; ++i) {
      int ct = wave * 2 + i - 2;
#pragma unroll
      for (int r = 0; r < 4; ++r)
        vt[wave - 1][i][4 * g + r][col] = acc[i][r] + bv[ct * 16 + 4 * g + r];
    }
  }
  __syncthreads();
  if (wave == 0) {
#pragma unroll
    for (int i = 0; i < 2; ++i) {
#pragma unroll
      for (int r = 0; r < 4; ++r) {
        int d = i * 16 + 4 * g + r;
        u16 hh, ll;
        split2(acc[i][r], hh, ll);
        size_t idx = ((size_t)b * kN + n0 + col) * kD + d;
        Qh[idx] = hh;
        Ql[idx] = ll;
      }
    }
  } else {
    int nt = n0 >> 5, p = (n0 >> 4) & 1;
#pragma unroll
    for (int i = 0; i < 2; ++i) {
      int ct = wave * 2 + i - 2;
      bf16x4 vh4, vl4;
#pragma unroll
      for (int j = 0; j < 4; ++j) {
        float v = vt[wave - 1][i][col][4 * g + j];
        u16 hh, ll;
        split2(v, hh, ll);
        vh4[j] = (short)hh;
        vl4[j] = (short)ll;
      }
      size_t base = ((((size_t)b * (kN / 32) + nt) * 8 + ct) * 64 + lane) * 8 + p * 4;
      *(bf16x4*)(Vph + base) = vh4;
      *(bf16x4*)(Vpl + base) = vl4;
    }
  }
}

// ---------------- pass1 v3: block n-32 (2 a-frags/wave), 4 waves split m; LDS merge.
// Stores e' = max*log2e + log2(rowsum): pass2's p = exp2(s*log2e - e') directly.
__global__ __launch_bounds__(256) void pass1_kernel(
    const u16* __restrict__ Qh, const u16* __restrict__ Ql,
    float* __restrict__ rme) {
  __shared__ float mxs[4][32], sms[4][32];
  int wave = threadIdx.x >> 6, lane = threadIdx.x & 63;
  int b = blockIdx.y;
  int n0 = blockIdx.x * 32;
  int col = lane & 15, g = lane >> 4;
  const u16* qbh = Qh + (size_t)b * kN * kD;
  const u16* qbl = Ql + (size_t)b * kN * kD;
  bf16x8 ah0 = *(const bf16x8*)(qbh + (size_t)(n0 + col) * kD + g * 8);
  bf16x8 al0 = *(const bf16x8*)(qbl + (size_t)(n0 + col) * kD + g * 8);
  bf16x8 ah1 = *(const bf16x8*)(qbh + (size_t)(n0 + 16 + col) * kD + g * 8);
  bf16x8 al1 = *(const bf16x8*)(qbl + (size_t)(n0 + 16 + col) * kD + g * 8);
  float mx[8], sm[8];
#pragma unroll
  for (int r = 0; r < 8; ++r) { mx[r] = -3.0e38f; sm[r] = 0.f; }
#pragma unroll 1
  for (int m0 = wave * 16; m0 < kN; m0 += 64) {
    bf16x8 bh = *(const bf16x8*)(qbh + (size_t)(m0 + col) * kD + g * 8);
    bf16x8 bl = *(const bf16x8*)(qbl + (size_t)(m0 + col) * kD + g * 8);
    f32x4 s0 = {}, s1 = {};
    s0 = mfma3(ah0, al0, bh, bl, s0);
    s1 = mfma3(ah1, al1, bh, bl, s1);
#pragma unroll
    for (int r = 0; r < 4; ++r) {
      float nm0 = fmaxf(mx[r], s0[r]);
      sm[r] = sm[r] * fexp2((mx[r] - nm0) * kL2E) + fexp2((s0[r] - nm0) * kL2E);
      mx[r] = nm0;
      float nm1 = fmaxf(mx[r + 4], s1[r]);
      sm[r + 4] = sm[r + 4] * fexp2((mx[r + 4] - nm1) * kL2E) + fexp2((s1[r] - nm1) * kL2E);
      mx[r + 4] = nm1;
    }
  }
#pragma unroll
  for (int o = 1; o < 16; o <<= 1) {
#pragma unroll
    for (int r = 0; r < 8; ++r) {
      float Mo = __shfl_xor(mx[r], o, 64);
      float So = __shfl_xor(sm[r], o, 64);
      float nm = fmaxf(mx[r], Mo);
      sm[r] = sm[r] * fexp2((mx[r] - nm) * kL2E) + So * fexp2((Mo - nm) * kL2E);
      mx[r] = nm;
    }
  }
  if (col == 0) {
#pragma unroll
    for (int r = 0; r < 4; ++r) {
      mxs[wave][4 * g + r] = mx[r];
      sms[wave][4 * g + r] = sm[r];
      mxs[wave][16 + 4 * g + r] = mx[r + 4];
      sms[wave][16 + 4 * g + r] = sm[r + 4];
    }
  }
  __syncthreads();
  if (threadIdx.x < 32) {
    int t = threadIdx.x;
    float M = mxs[0][t], S = sms[0][t];
#pragma unroll
    for (int w = 1; w < 4; ++w) {
      float Mo = mxs[w][t], So = sms[w][t];
      float nm = fmaxf(M, Mo);
      S = S * fexp2((M - nm) * kL2E) + So * fexp2((Mo - nm) * kL2E);
      M = nm;
    }
    rme[(size_t)b * kN + n0 + t] = M * kL2E + flog2(S);
  }
}

// ---------------- pass2 v10: block m-32, 256 thr, 2 m-frags/wave (V register-reuse),
// p = exp2(s*log2e - e'), v_perm packing. No in-loop barriers; LDS end-combine.
__global__ __launch_bounds__(256) void pass2_kernel(
    const u16* __restrict__ Qh, const u16* __restrict__ Ql,
    const u16* __restrict__ Vph, const u16* __restrict__ Vpl,
    const float* __restrict__ rme,
    const u16* __restrict__ xh, const u16* __restrict__ xl,
    u16* __restrict__ yth, u16* __restrict__ ytl) {
  __shared__ f32x4 accs[4][8][64];
  __shared__ float csl[2][4][16];
  int wave = threadIdx.x >> 6, lane = threadIdx.x & 63;
  int b = blockIdx.y;
  int m0 = blockIdx.x * 32;
  int col = lane & 15, g = lane >> 4;
  const u16* qbh = Qh + (size_t)b * kN * kD;
  const u16* qbl = Ql + (size_t)b * kN * kD;
  const float* rmb = rme + (size_t)b * kN;
  bf16x8 bmh0 = *(const bf16x8*)(qbh + (size_t)(m0 + col) * kD + g * 8);
  bf16x8 bml0 = *(const bf16x8*)(qbl + (size_t)(m0 + col) * kD + g * 8);
  bf16x8 bmh1 = *(const bf16x8*)(qbh + (size_t)(m0 + 16 + col) * kD + g * 8);
  bf16x8 bml1 = *(const bf16x8*)(qbl + (size_t)(m0 + 16 + col) * kD + g * 8);
  const u16* vbh = Vph + (size_t)b * (kN / 32) * 4096;
  const u16* vbl = Vpl + (size_t)b * (kN / 32) * 4096;
  f32x4 accA[8] = {}, accB[8] = {};
  float csA = 0.f, csB = 0.f;
#pragma unroll 1
  for (int nn = wave * 32; nn < kN; nn += 128) {
    bf16x8 ah0 = *(const bf16x8*)(qbh + (size_t)(nn + col) * kD + g * 8);
    bf16x8 al0 = *(const bf16x8*)(qbl + (size_t)(nn + col) * kD + g * 8);
    bf16x8 ah1 = *(const bf16x8*)(qbh + (size_t)(nn + 16 + col) * kD + g * 8);
    bf16x8 al1 = *(const bf16x8*)(qbl + (size_t)(nn + 16 + col) * kD + g * 8);
    f32x4 sA0 = {}, sA1 = {}, sB0 = {}, sB1 = {};
    sA0 = mfma3(ah0, al0, bmh0, bml0, sA0);
    sA1 = mfma3(ah1, al1, bmh0, bml0, sA1);
    sB0 = mfma3(ah0, al0, bmh1, bml1, sB0);
    sB1 = mfma3(ah1, al1, bmh1, bml1, sB1);
    float pA[8], pB[8];
#pragma unroll
    for (int r = 0; r < 4; ++r) {
      float e0 = rmb[nn + 4 * g + r];
      float e1 = rmb[nn + 16 + 4 * g + r];
      pA[r] = fexp2(sA0[r] * kL2E - e0);
      pA[r + 4] = fexp2(sA1[r] * kL2E - e1);
      pB[r] = fexp2(sB0[r] * kL2E - e0);
      pB[r + 4] = fexp2(sB1[r] * kL2E - e1);
      csA += pA[r] + pA[r + 4];
      csB += pB[r] + pB[r + 4];
    }
    u32x4 Ahw, Alw, Bhw, Blw;
#pragma unroll
    for (int k2 = 0; k2 < 4; ++k2) {
      u32 h0, l0, h1, l1;
      splitpair(pA[2 * k2], pA[2 * k2 + 1], h0, l0);
      splitpair(pB[2 * k2], pB[2 * k2 + 1], h1, l1);
      Ahw[k2] = h0; Alw[k2] = l0;
      Bhw[k2] = h1; Blw[k2] = l1;
    }
    bf16x8 bAh = __builtin_bit_cast(bf16x8, Ahw);
    bf16x8 bAl = __builtin_bit_cast(bf16x8, Alw);
    bf16x8 bBh = __builtin_bit_cast(bf16x8, Bhw);
    bf16x8 bBl = __builtin_bit_cast(bf16x8, Blw);
    size_t vtile = (size_t)(nn >> 5) * 4096;
#pragma unroll
    for (int ct = 0; ct < 8; ++ct) {
      size_t off = vtile + ((size_t)ct * 64 + lane) * 8;
      bf16x8 a8h = *(const bf16x8*)(vbh + off);
      bf16x8 a8l = *(const bf16x8*)(vbl + off);
      accA[ct] = mfma3(a8h, a8l, bAh, bAl, accA[ct]);
      accB[ct] = mfma3(a8h, a8l, bBh, bBl, accB[ct]);
    }
  }
  csA += __shfl_xor(csA, 16, 64);
  csA += __shfl_xor(csA, 32, 64);
  csB += __shfl_xor(csB, 16, 64);
  csB += __shfl_xor(csB, 32, 64);
  if (lane < 16) {
    csl[0][wave][lane] = csA;
    csl[1][wave][lane] = csB;
  }
  // ---- phase A combine + write (rows m0+col)
#pragma unroll
  for (int ct = 0; ct < 8; ++ct) accs[wave][ct][lane] = accA[ct];
  __syncthreads();
  {
    float inv = 1.0f / (1e-9f + csl[0][0][col] + csl[0][1][col] + csl[0][2][col] + csl[0][3][col]);
    const u16* xrh = xh + ((size_t)b * kN + m0 + col) * kC;
    const u16* xrl = xl + ((size_t)b * kN + m0 + col) * kC;
#pragma unroll
    for (int i = 0; i < 2; ++i) {
      int ct = wave * 2 + i;
      f32x4 a = accs[0][ct][lane];
      a += accs[1][ct][lane];
      a += accs[2][ct][lane];
      a += accs[3][ct][lane];
      bf16x4 xvh = *(const bf16x4*)(xrh + ct * 16 + 4 * g);
      bf16x4 xvl = *(const bf16x4*)(xrl + ct * 16 + 4 * g);
#pragma unroll
      for (int r = 0; r < 4; ++r) {
        float xv = bf2f((u16)xvh[r]) + bf2f((u16)xvl[r]);
        float y = xv - a[r] * inv;
        u16 hh, ll;
        split2(y, hh, ll);
        size_t idx = ((size_t)b * kN + m0 + col) * kC + ct * 16 + 4 * g + r;
        yth[idx] = hh;
        ytl[idx] = ll;
      }
    }
  }
  __syncthreads();
  // ---- phase B combine + write (rows m0+16+col)
#pragma unroll
  for (int ct = 0; ct < 8; ++ct) accs[wave][ct][lane] = accB[ct];
  __syncthreads();
  {
    float inv = 1.0f / (1e-9f + csl[1][0][col] + csl[1][1][col] + csl[1][2][col] + csl[1][3][col]);
    const u16* xrh = xh + ((size_t)b * kN + m0 + 16 + col) * kC;
    const u16* xrl = xl + ((size_t)b * kN + m0 + 16 + col) * kC;
#pragma unroll
    for (int i = 0; i < 2; ++i) {
      int ct = wave * 2 + i;
      f32x4 a = accs[0][ct][lane];
      a += accs[1][ct][lane];
      a += accs[2][ct][lane];
      a += accs[3][ct][lane];
      bf16x4 xvh = *(const bf16x4*)(xrh + ct * 16 + 4 * g);
      bf16x4 xvl = *(const bf16x4*)(xrl + ct * 16 + 4 * g);
#pragma unroll
      for (int r = 0; r < 4; ++r) {
        float xv = bf2f((u16)xvh[r]) + bf2f((u16)xvl[r]);
        float y = xv - a[r] * inv;
        u16 hh, ll;
        split2(y, hh, ll);
        size_t idx = ((size_t)b * kN + m0 + 16 + col) * kC + ct * 16 + 4 * g + r;
        yth[idx] = hh;
        ytl[idx] = ll;
      }
    }
  }
}

// ---------------- conv GEMM: 4 waves x 2 output-tiles, 16 n-cols per block
__global__ __launch_bounds__(256) void tconv_kernel(
    const u16* __restrict__ inh, const u16* __restrict__ inl,
    const u16* __restrict__ wh, const u16* __restrict__ wl,
    const float* __restrict__ bias, float* __restrict__ u,
    long ustride, long uoff) {
  int wave = threadIdx.x >> 6, lane = threadIdx.x & 63;
  int b = blockIdx.y;
  int n0 = blockIdx.x * 16;
  int col = lane & 15, g = lane >> 4;
  f32x4 acc[2] = {};
  const u16* xrh = inh + ((size_t)b * kN + n0 + col) * kC + g * 8;
  const u16* xrl = inl + ((size_t)b * kN + n0 + col) * kC + g * 8;
#pragma unroll
  for (int kk = 0; kk < 4; ++kk) {
    bf16x8 bh = *(const bf16x8*)(xrh + kk * 32);
    bf16x8 bl = *(const bf16x8*)(xrl + kk * 32);
#pragma unroll
    for (int i = 0; i < 2; ++i) {
      int ot = wave * 2 + i;
      bf16x8 ah = *(const bf16x8*)(wh + (size_t)(ot * 16 + col) * kC + kk * 32 + g * 8);
      bf16x8 al = *(const bf16x8*)(wl + (size_t)(ot * 16 + col) * kC + kk * 32 + g * 8);
      acc[i] = mfma3(ah, al, bh, bl, acc[i]);
    }
  }
#pragma unroll
  for (int i = 0; i < 2; ++i) {
    int ot = wave * 2 + i;
#pragma unroll
    for (int r = 0; r < 4; ++r) {
      int c = ot * 16 + 4 * g + r;
      float v = acc[i][r] + (bias ? bias[c] : 0.f);
      u[(size_t)b * ustride + uoff + (size_t)c * kN + n0 + col] = v;
    }
  }
}

// ---------------- BN stats stage A: per-(channel, chunk) fp64 partial sums
__global__ __launch_bounds__(256) void bn_part_kernel(const float* __restrict__ u,
                                                      long ustride, long uoff,
                                                      double* __restrict__ part) {
  int c = blockIdx.x, chunk = blockIdx.y;  // 8 chunks of 2048 elements
  __shared__ double rs[4], rss[4];
  double s = 0.0, ss = 0.0;
  int base = chunk * 2048;
  for (int j = threadIdx.x; j < 2048; j += 256) {
    int i = base + j, b = i >> 12, n = i & (kN - 1);
    float v = u[(size_t)b * ustride + uoff + (size_t)c * kN + n];
    s += (double)v;
    ss += (double)v * (double)v;
  }
#pragma unroll
  for (int o = 1; o < 64; o <<= 1) {
    s += __shfl_xor(s, o, 64);
    ss += __shfl_xor(ss, o, 64);
  }
  int wid = threadIdx.x >> 6, lane = threadIdx.x & 63;
  if (lane == 0) { rs[wid] = s; rss[wid] = ss; }
  __syncthreads();
  if (threadIdx.x == 0) {
    part[(size_t)(c * 8 + chunk) * 2 + 0] = rs[0] + rs[1] + rs[2] + rs[3];
    part[(size_t)(c * 8 + chunk) * 2 + 1] = rss[0] + rss[1] + rss[2] + rss[3];
  }
}

// ---------------- BN stats stage B: finalize mean/rstd per channel
__global__ void bn_fin_kernel(const double* __restrict__ part, float* __restrict__ stat) {
  int c = threadIdx.x;  // 128 threads, 1 block
  double S = 0.0, SS = 0.0;
#pragma unroll
  for (int k = 0; k < 8; ++k) {
    S += part[(size_t)(c * 8 + k) * 2 + 0];
    SS += part[(size_t)(c * 8 + k) * 2 + 1];
  }
  double mean = S / (double)(kB * kN);
  double var = SS / (double)(kB * kN) - mean * mean;
  if (var < 0.0) var = 0.0;
  stat[c] = (float)mean;
  stat[kC + c] = rsqrtf((float)var + 1e-5f);
}

// ---------------- fused bn_final + next-layer prep:
// y = relu(BN(u)) [+ h + e]; out = y; xh/xl = split(y + e)  (transpose via LDS)
__global__ __launch_bounds__(256) void bnprep_kernel(
    const float* __restrict__ u, long ustride, long uoff,
    const float* __restrict__ stat,
    const float* __restrict__ g, const float* __restrict__ bb,
    const float* __restrict__ h, long hstride, long hoff, int use_res,
    const float* __restrict__ xyz, const float* __restrict__ pw,
    const float* __restrict__ pb,
    float* __restrict__ out, long ostride, long ooff,
    u16* __restrict__ xh, u16* __restrict__ xl) {
  __shared__ float t[32][33];
  int n0 = blockIdx.x * 32, c0 = blockIdx.y * 32, b = blockIdx.z;
  int tx = threadIdx.x & 31, ty = threadIdx.x >> 5;  // 32 x 8
  const float* xp = xyz + ((size_t)b * kN + n0 + tx) * 3;
  float xv0 = xp[0], xv1 = xp[1], xv2 = xp[2];
#pragma unroll
  for (int i = 0; i < 4; ++i) {
    int c = c0 + ty + i * 8;
    float e = pw[c * 3 + 0] * xv0 + pw[c * 3 + 1] * xv1 + pw[c * 3 + 2] * xv2 + pb[c];
    float y = (u[(size_t)b * ustride + uoff + (size_t)c * kN + n0 + tx] - stat[c]) *
                  stat[kC + c] * g[c] + bb[c];
    y = fmaxf(y, 0.f);
    if (use_res) y += h[(size_t)b * hstride + hoff + (size_t)c * kN + n0 + tx] + e;
    out[(size_t)b * ostride + ooff + (size_t)c * kN + n0 + tx] = y;
    t[ty + i * 8][tx] = y + e;  // next layer's xa
  }
  __syncthreads();
#pragma unroll
  for (int i = 0; i < 4; ++i) {
    int n = n0 + ty + i * 8, c = c0 + tx;
    u16 hh, ll;
    split2(t[tx][ty + i * 8], hh, ll);
    size_t idx = ((size_t)b * kN + n) * kC + c;
    xh[idx] = hh;
    xl[idx] = ll;
  }
}

extern "C" void kernel_launch(void* const* d_in, const int* in_sizes, int n_in,
                              void* d_out, int out_size, void* d_ws, size_t ws_size,
                              hipStream_t stream) {
  const float* x = (const float*)d_in[0];
  const float* xyz = (const float*)d_in[1];
  const float* conv1_w = (const float*)d_in[2];
  const float* bn1_g = (const float*)d_in[3];
  const float* bn1_b = (const float*)d_in[4];
  const float* pos_w = (const float*)d_in[5];
  const float* pos_b = (const float*)d_in[6];
  const float* sa_wqk = (const float*)d_in[7];
  const float* sa_wv = (const float*)d_in[8];
  const float* sa_bv = (const float*)d_in[9];
  const float* sa_wt = (const float*)d_in[10];
  const float* sa_bt = (const float*)d_in[11];
  const float* sa_bng = (const float*)d_in[12];
  const float* sa_bnb = (const float*)d_in[13];
  float* out = (float*)d_out;
  char* ws = (char*)d_ws;
  const size_t MB = (size_t)1 << 20;

  const size_t NEED = 28 * MB;
  if (ws_size < NEED) {
    float val = 100.0f + (float)(ws_size >> 20);
    sentinel_kernel<<<dim3((out_size + 255) / 256), dim3(256), 0, stream>>>(out, val, out_size);
    return;
  }

  u16* xh = (u16*)(ws);                  // [0,4MB)
  u16* xl = (u16*)(ws + 4 * MB);         // [4,8MB)
  u16* yth = (u16*)(ws + 8 * MB);        // [8,12MB)
  u16* ytl = (u16*)(ws + 12 * MB);       // [12,16MB)
  u16* Vph = (u16*)(ws + 16 * MB);       // [16,20MB)  packed V hi
  u16* Vpl = (u16*)(ws + 20 * MB);       // [20,24MB)  packed V lo
  u16* Qh = (u16*)(ws + 24 * MB);        // [24,25MB)
  u16* Ql = (u16*)(ws + 25 * MB);        // [25,26MB)
  u16* wa = (u16*)(ws + 26 * MB);        // weight split arena [26,27MB)
  size_t woff = 0;
  u16* c1h = wa + woff; woff += 16384;
  u16* c1l = wa + woff; woff += 16384;
  u16* qkh = wa + woff; woff += 5 * 32 * 128;
  u16* qkl = wa + woff; woff += 5 * 32 * 128;
  u16* wvh = wa + woff; woff += 5 * 128 * 128;
  u16* wvl = wa + woff; woff += 5 * 128 * 128;
  u16* wth = wa + woff; woff += 5 * 128 * 128;
  u16* wtl = wa + woff; woff += 5 * 128 * 128;
  float* rme = (float*)(ws + 27 * MB);                  // 64 KB
  float* stat = (float*)(ws + 27 * MB + 131072);        // 1 KB
  double* part = (double*)(ws + 27 * MB + 196608);      // 16 KB

  dim3 blk(256);

  cvt_split_kernel<<<dim3(64), blk, 0, stream>>>(conv1_w, c1h, c1l, 16384);
  cvt_split_kernel<<<dim3(80), blk, 0, stream>>>(sa_wqk, qkh, qkl, 20480);
  cvt_split_kernel<<<dim3(320), blk, 0, stream>>>(sa_wv, wvh, wvl, 81920);
  cvt_split_kernel<<<dim3(320), blk, 0, stream>>>(sa_wt, wth, wtl, 81920);

  const long sbo = (long)kCO * kN;
  const long slice = (long)kC * kN;
  const long h0off = 4 * slice;  // h0 parked in layer-4 slice (dead after layer-0 reads)

  // ---- setup: conv1 + BN + relu -> h0; bnprep also emits layer-0 xa (h0 + emb)
  prep_kernel<<<dim3(kN / 32, kC / 32, kB), blk, 0, stream>>>(x, slice, 0, xh, xl);
  tconv_kernel<<<dim3(kN / 16, kB), blk, 0, stream>>>(
      xh, xl, c1h, c1l, nullptr, out, sbo, 0);
  bn_part_kernel<<<dim3(kC, 8), blk, 0, stream>>>(out, sbo, 0, part);
  bn_fin_kernel<<<dim3(1), dim3(128), 0, stream>>>(part, stat);
  bnprep_kernel<<<dim3(kN / 32, kC / 32, kB), blk, 0, stream>>>(
      out, sbo, 0, stat, bn1_g, bn1_b, nullptr, 0, 0, 0, xyz, pos_w, pos_b,
      out, sbo, h0off, xh, xl);

  long hoff = h0off;
  for (int i = 0; i < kL; ++i) {
    long uoff = (long)i * slice;  // layer-i pre-BN u lives in out slice i (in-place BN)
    qv_kernel<<<dim3(kN / 16, kB), dim3(320), 0, stream>>>(
        xh, xl, qkh + (size_t)i * kD * kC, qkl + (size_t)i * kD * kC,
        wvh + (size_t)i * kC * kC, wvl + (size_t)i * kC * kC,
        sa_bv + (size_t)i * kC, Qh, Ql, Vph, Vpl);
    pass1_kernel<<<dim3(kN / 32, kB), blk, 0, stream>>>(Qh, Ql, rme);
    pass2_kernel<<<dim3(kN / 32, kB), blk, 0, stream>>>(
        Qh, Ql, Vph, Vpl, rme, xh, xl, yth, ytl);
    tconv_kernel<<<dim3(kN / 16, kB), blk, 0, stream>>>(
        yth, ytl, wth + (size_t)i * kC * kC, wtl + (size_t)i * kC * kC,
        sa_bt + (size_t)i * kC, out, sbo, uoff);
    bn_part_kernel<<<dim3(kC, 8), blk, 0, stream>>>(out, sbo, uoff, part);
    bn_fin_kernel<<<dim3(1), dim3(128), 0, stream>>>(part, stat);
    bnprep_kernel<<<dim3(kN / 32, kC / 32, kB), blk, 0, stream>>>(
        out, sbo, uoff, stat, sa_bng + (size_t)i * kC, sa_bnb + (size_t)i * kC,
        out, sbo, hoff, 1, xyz, pos_w, pos_b, out, sbo, uoff, xh, xl);
    hoff = uoff;
  }
}

// Round 19
// 811.947 us; speedup vs baseline: 1.2484x; 1.0211x over previous
//
#include <hip/hip_runtime.h>

#define kB 4
#define kC 128
#define kN 4096
#define kD 32
#define kL 5
#define kCO 640
#define kL2E 1.4426950408889634f

typedef float f32x4 __attribute__((ext_vector_type(4)));
typedef short bf16x4 __attribute__((ext_vector_type(4)));
typedef short bf16x8 __attribute__((ext_vector_type(8)));
typedef unsigned u32;
typedef u32 u32x4 __attribute__((ext_vector_type(4)));
typedef unsigned short u16;

__device__ __forceinline__ float bf2f(u16 u) {
  unsigned v = ((unsigned)u) << 16;
  return __builtin_bit_cast(float, v);
}
__device__ __forceinline__ u16 f2bf(float f) {
  unsigned u = __builtin_bit_cast(unsigned, f);
  u += 0x7fffu + ((u >> 16) & 1u);
  return (u16)(u >> 16);
}
__device__ __forceinline__ void split2(float v, u16& hi, u16& lo) {
  hi = f2bf(v);
  lo = f2bf(v - bf2f(hi));
}
// raw v_exp_f32 / v_log_f32 (libm versions add ~10 fixup ops without -ffast-math)
__device__ __forceinline__ float fexp2(float x) {
#if __has_builtin(__builtin_amdgcn_exp2f)
  return __builtin_amdgcn_exp2f(x);
#else
  return exp2f(x);
#endif
}
__device__ __forceinline__ float flog2(float x) {
#if __has_builtin(__builtin_amdgcn_logf)
  return __builtin_amdgcn_logf(x);
#else
  return log2f(x);
#endif
}
// pack pair (a,b) -> hi-word (trunc bf16s: [bf16(a) | bf16(b)<<16]) and lo-word
// (trunc of residuals). v_perm_b32 gathers bytes [a2 a3 b2 b3] in 1 instruction.
__device__ __forceinline__ u32 pkhalves(u32 a, u32 b) {
#if __has_builtin(__builtin_amdgcn_perm)
  return __builtin_amdgcn_perm(b, a, 0x07060302u);
#else
  return (a >> 16) | (b & 0xffff0000u);
#endif
}
__device__ __forceinline__ void splitpair(float a, float b, u32& hw, u32& lw) {
  u32 ua = __builtin_bit_cast(u32, a), ub = __builtin_bit_cast(u32, b);
  hw = pkhalves(ua, ub);
  float la = a - __builtin_bit_cast(float, ua & 0xffff0000u);
  float lb = b - __builtin_bit_cast(float, ub & 0xffff0000u);
  lw = pkhalves(__builtin_bit_cast(u32, la), __builtin_bit_cast(u32, lb));
}
// s += A*B with split operands: ah*bh + ah*bl + al*bh (drops al*bl, ~2^-16 rel)
__device__ __forceinline__ f32x4 mfma3(bf16x8 ah, bf16x8 al, bf16x8 bh, bf16x8 bl, f32x4 c) {
  c = __builtin_amdgcn_mfma_f32_16x16x32_bf16(ah, bh, c, 0, 0, 0);
  c = __builtin_amdgcn_mfma_f32_16x16x32_bf16(ah, bl, c, 0, 0, 0);
  c = __builtin_amdgcn_mfma_f32_16x16x32_bf16(al, bh, c, 0, 0, 0);
  return c;
}

// ---------------- sentinel (ws too small): encodes ws MB into output
__global__ void sentinel_kernel(float* out, float val, int total) {
  int i = blockIdx.x * 256 + threadIdx.x;
  if (i < total) out[i] = val;
}

// ---------------- split ALL fp32 weight arrays -> bf16 hi/lo arenas (one launch)
__global__ void cvt_all_kernel(const float* __restrict__ s0, const float* __restrict__ s1,
                               const float* __restrict__ s2, const float* __restrict__ s3,
                               u16* h0, u16* l0, u16* h1, u16* l1,
                               u16* h2, u16* l2, u16* h3, u16* l3) {
  int i = blockIdx.x * 256 + threadIdx.x;
  const float* s;
  u16 *dh, *dl;
  int off;
  if (i < 16384) { s = s0; dh = h0; dl = l0; off = i; }
  else if (i < 36864) { s = s1; dh = h1; dl = l1; off = i - 16384; }
  else if (i < 118784) { s = s2; dh = h2; dl = l2; off = i - 36864; }
  else if (i < 200704) { s = s3; dh = h3; dl = l3; off = i - 118784; }
  else return;
  u16 h, l;
  split2(s[off], h, l);
  dh[off] = h;
  dl[off] = l;
}

// ---------------- xh/xl[b][n][c] = split(h[b][c][n])   (transpose + split; setup only)
__global__ __launch_bounds__(256) void prep_kernel(
    const float* __restrict__ h, long hstride, long hoff,
    u16* __restrict__ xh, u16* __restrict__ xl) {
  __shared__ float t[32][33];
  int n0 = blockIdx.x * 32, c0 = blockIdx.y * 32, b = blockIdx.z;
  int tx = threadIdx.x & 31, ty = threadIdx.x >> 5;  // 32 x 8
#pragma unroll
  for (int i = 0; i < 4; ++i) {
    int c = c0 + ty + i * 8;
    t[ty + i * 8][tx] = h[(size_t)b * hstride + hoff + (size_t)c * kN + n0 + tx];
  }
  __syncthreads();
#pragma unroll
  for (int i = 0; i < 4; ++i) {
    int n = n0 + ty + i * 8, c = c0 + tx;
    u16 hh, ll;
    split2(t[tx][ty + i * 8], hh, ll);
    size_t idx = ((size_t)b * kN + n) * kC + c;
    xh[idx] = hh;
    xl[idx] = ll;
  }
}

// ---------------- QV GEMM: 5 waves x 2 tiles, 16 n-cols per block.
// V written in FRAGMENT-PACKED layout: Vp[b][nt=n/32][ct=c/16][lane][8 bf16],
// lane=(g<<4)|col holds V[ct*16+col][nt*32+4g..+3] (p=0) and [nt*32+16+4g..+3] (p=1).
__global__ __launch_bounds__(320) void qv_kernel(
    const u16* __restrict__ xh, const u16* __restrict__ xl,
    const u16* __restrict__ wqkh, const u16* __restrict__ wqkl,
    const u16* __restrict__ wvh, const u16* __restrict__ wvl,
    const float* __restrict__ bv,
    u16* __restrict__ Qh, u16* __restrict__ Ql,
    u16* __restrict__ Vph, u16* __restrict__ Vpl) {
  __shared__ float vt[4][2][16][17];
  int wave = threadIdx.x >> 6, lane = threadIdx.x & 63;  // wave 0..4
  int b = blockIdx.y;
  int n0 = blockIdx.x * 16;
  int col = lane & 15, g = lane >> 4;
  f32x4 acc[2] = {};
  const u16* xrh = xh + ((size_t)b * kN + n0 + col) * kC + g * 8;
  const u16* xrl = xl + ((size_t)b * kN + n0 + col) * kC + g * 8;
#pragma unroll
  for (int kk = 0; kk < 4; ++kk) {
    bf16x8 bh = *(const bf16x8*)(xrh + kk * 32);
    bf16x8 bl = *(const bf16x8*)(xrl + kk * 32);
#pragma unroll
    for (int i = 0; i < 2; ++i) {
      int ot = wave * 2 + i;
      size_t wi = (ot < 2) ? ((size_t)(ot * 16 + col) * kC) : ((size_t)((ot - 2) * 16 + col) * kC);
      const u16* wsh = (ot < 2) ? (wqkh + wi) : (wvh + wi);
      const u16* wsl = (ot < 2) ? (wqkl + wi) : (wvl + wi);
      bf16x8 ah = *(const bf16x8*)(wsh + kk * 32 + g * 8);
      bf16x8 al = *(const bf16x8*)(wsl + kk * 32 + g * 8);
      acc[i] = mfma3(ah, al, bh, bl, acc[i]);
    }
  }
  if (wave > 0) {
#pragma unroll
    for (int i = 0; i < 2; ++i) {
      int ct = wave * 2 + i - 2;
#pragma unroll
      for (int r = 0; r < 4; ++r)
        vt[wave - 1][i][4 * g + r][col] = acc[i][r] + bv[ct * 16 + 4 * g + r];
    }
  }
  __syncthreads();
  if (wave == 0) {
#pragma unroll
    for (int i = 0; i < 2; ++i) {
#pragma unroll
      for (int r = 0; r < 4; ++r) {
        int d = i * 16 + 4 * g + r;
        u16 hh, ll;
        split2(acc[i][r], hh, ll);
        size_t idx = ((size_t)b * kN + n0 + col) * kD + d;
        Qh[idx] = hh;
        Ql[idx] = ll;
      }
    }
  } else {
    int nt = n0 >> 5, p = (n0 >> 4) & 1;
#pragma unroll
    for (int i = 0; i < 2; ++i) {
      int ct = wave * 2 + i - 2;
      bf16x4 vh4, vl4;
#pragma unroll
      for (int j = 0; j < 4; ++j) {
        float v = vt[wave - 1][i][col][4 * g + j];
        u16 hh, ll;
        split2(v, hh, ll);
        vh4[j] = (short)hh;
        vl4[j] = (short)ll;
      }
      size_t base = ((((size_t)b * (kN / 32) + nt) * 8 + ct) * 64 + lane) * 8 + p * 4;
      *(bf16x4*)(Vph + base) = vh4;
      *(bf16x4*)(Vpl + base) = vl4;
    }
  }
}

// ---------------- pass1 v3: block n-32 (2 a-frags/wave), 4 waves split m; LDS merge.
// Stores e' = max*log2e + log2(rowsum): pass2's p = exp2(s*log2e - e') directly.
__global__ __launch_bounds__(256) void pass1_kernel(
    const u16* __restrict__ Qh, const u16* __restrict__ Ql,
    float* __restrict__ rme) {
  __shared__ float mxs[4][32], sms[4][32];
  int wave = threadIdx.x >> 6, lane = threadIdx.x & 63;
  int b = blockIdx.y;
  int n0 = blockIdx.x * 32;
  int col = lane & 15, g = lane >> 4;
  const u16* qbh = Qh + (size_t)b * kN * kD;
  const u16* qbl = Ql + (size_t)b * kN * kD;
  bf16x8 ah0 = *(const bf16x8*)(qbh + (size_t)(n0 + col) * kD + g * 8);
  bf16x8 al0 = *(const bf16x8*)(qbl + (size_t)(n0 + col) * kD + g * 8);
  bf16x8 ah1 = *(const bf16x8*)(qbh + (size_t)(n0 + 16 + col) * kD + g * 8);
  bf16x8 al1 = *(const bf16x8*)(qbl + (size_t)(n0 + 16 + col) * kD + g * 8);
  float mx[8], sm[8];
#pragma unroll
  for (int r = 0; r < 8; ++r) { mx[r] = -3.0e38f; sm[r] = 0.f; }
#pragma unroll 1
  for (int m0 = wave * 16; m0 < kN; m0 += 64) {
    bf16x8 bh = *(const bf16x8*)(qbh + (size_t)(m0 + col) * kD + g * 8);
    bf16x8 bl = *(const bf16x8*)(qbl + (size_t)(m0 + col) * kD + g * 8);
    f32x4 s0 = {}, s1 = {};
    s0 = mfma3(ah0, al0, bh, bl, s0);
    s1 = mfma3(ah1, al1, bh, bl, s1);
#pragma unroll
    for (int r = 0; r < 4; ++r) {
      float nm0 = fmaxf(mx[r], s0[r]);
      sm[r] = sm[r] * fexp2((mx[r] - nm0) * kL2E) + fexp2((s0[r] - nm0) * kL2E);
      mx[r] = nm0;
      float nm1 = fmaxf(mx[r + 4], s1[r]);
      sm[r + 4] = sm[r + 4] * fexp2((mx[r + 4] - nm1) * kL2E) + fexp2((s1[r] - nm1) * kL2E);
      mx[r + 4] = nm1;
    }
  }
#pragma unroll
  for (int o = 1; o < 16; o <<= 1) {
#pragma unroll
    for (int r = 0; r < 8; ++r) {
      float Mo = __shfl_xor(mx[r], o, 64);
      float So = __shfl_xor(sm[r], o, 64);
      float nm = fmaxf(mx[r], Mo);
      sm[r] = sm[r] * fexp2((mx[r] - nm) * kL2E) + So * fexp2((Mo - nm) * kL2E);
      mx[r] = nm;
    }
  }
  if (col == 0) {
#pragma unroll
    for (int r = 0; r < 4; ++r) {
      mxs[wave][4 * g + r] = mx[r];
      sms[wave][4 * g + r] = sm[r];
      mxs[wave][16 + 4 * g + r] = mx[r + 4];
      sms[wave][16 + 4 * g + r] = sm[r + 4];
    }
  }
  __syncthreads();
  if (threadIdx.x < 32) {
    int t = threadIdx.x;
    float M = mxs[0][t], S = sms[0][t];
#pragma unroll
    for (int w = 1; w < 4; ++w) {
      float Mo = mxs[w][t], So = sms[w][t];
      float nm = fmaxf(M, Mo);
      S = S * fexp2((M - nm) * kL2E) + So * fexp2((Mo - nm) * kL2E);
      M = nm;
    }
    rme[(size_t)b * kN + n0 + t] = M * kL2E + flog2(S);
  }
}

// ---------------- pass2 v10: block m-32, 256 thr, 2 m-frags/wave (V register-reuse),
// p = exp2(s*log2e - e'), v_perm packing. No in-loop barriers; LDS end-combine.
__global__ __launch_bounds__(256) void pass2_kernel(
    const u16* __restrict__ Qh, const u16* __restrict__ Ql,
    const u16* __restrict__ Vph, const u16* __restrict__ Vpl,
    const float* __restrict__ rme,
    const u16* __restrict__ xh, const u16* __restrict__ xl,
    u16* __restrict__ yth, u16* __restrict__ ytl) {
  __shared__ f32x4 accs[4][8][64];
  __shared__ float csl[2][4][16];
  int wave = threadIdx.x >> 6, lane = threadIdx.x & 63;
  int b = blockIdx.y;
  int m0 = blockIdx.x * 32;
  int col = lane & 15, g = lane >> 4;
  const u16* qbh = Qh + (size_t)b * kN * kD;
  const u16* qbl = Ql + (size_t)b * kN * kD;
  const float* rmb = rme + (size_t)b * kN;
  bf16x8 bmh0 = *(const bf16x8*)(qbh + (size_t)(m0 + col) * kD + g * 8);
  bf16x8 bml0 = *(const bf16x8*)(qbl + (size_t)(m0 + col) * kD + g * 8);
  bf16x8 bmh1 = *(const bf16x8*)(qbh + (size_t)(m0 + 16 + col) * kD + g * 8);
  bf16x8 bml1 = *(const bf16x8*)(qbl + (size_t)(m0 + 16 + col) * kD + g * 8);
  const u16* vbh = Vph + (size_t)b * (kN / 32) * 4096;
  const u16* vbl = Vpl + (size_t)b * (kN / 32) * 4096;
  f32x4 accA[8] = {}, accB[8] = {};
  float csA = 0.f, csB = 0.f;
#pragma unroll 1
  for (int nn = wave * 32; nn < kN; nn += 128) {
    bf16x8 ah0 = *(const bf16x8*)(qbh + (size_t)(nn + col) * kD + g * 8);
    bf16x8 al0 = *(const bf16x8*)(qbl + (size_t)(nn + col) * kD + g * 8);
    bf16x8 ah1 = *(const bf16x8*)(qbh + (size_t)(nn + 16 + col) * kD + g * 8);
    bf16x8 al1 = *(const bf16x8*)(qbl + (size_t)(nn + 16 + col) * kD + g * 8);
    f32x4 sA0 = {}, sA1 = {}, sB0 = {}, sB1 = {};
    sA0 = mfma3(ah0, al0, bmh0, bml0, sA0);
    sA1 = mfma3(ah1, al1, bmh0, bml0, sA1);
    sB0 = mfma3(ah0, al0, bmh1, bml1, sB0);
    sB1 = mfma3(ah1, al1, bmh1, bml1, sB1);
    float pA[8], pB[8];
#pragma unroll
    for (int r = 0; r < 4; ++r) {
      float e0 = rmb[nn + 4 * g + r];
      float e1 = rmb[nn + 16 + 4 * g + r];
      pA[r] = fexp2(sA0[r] * kL2E - e0);
      pA[r + 4] = fexp2(sA1[r] * kL2E - e1);
      pB[r] = fexp2(sB0[r] * kL2E - e0);
      pB[r + 4] = fexp2(sB1[r] * kL2E - e1);
      csA += pA[r] + pA[r + 4];
      csB += pB[r] + pB[r + 4];
    }
    u32x4 Ahw, Alw, Bhw, Blw;
#pragma unroll
    for (int k2 = 0; k2 < 4; ++k2) {
      u32 h0, l0, h1, l1;
      splitpair(pA[2 * k2], pA[2 * k2 + 1], h0, l0);
      splitpair(pB[2 * k2], pB[2 * k2 + 1], h1, l1);
      Ahw[k2] = h0; Alw[k2] = l0;
      Bhw[k2] = h1; Blw[k2] = l1;
    }
    bf16x8 bAh = __builtin_bit_cast(bf16x8, Ahw);
    bf16x8 bAl = __builtin_bit_cast(bf16x8, Alw);
    bf16x8 bBh = __builtin_bit_cast(bf16x8, Bhw);
    bf16x8 bBl = __builtin_bit_cast(bf16x8, Blw);
    size_t vtile = (size_t)(nn >> 5) * 4096;
#pragma unroll
    for (int ct = 0; ct < 8; ++ct) {
      size_t off = vtile + ((size_t)ct * 64 + lane) * 8;
      bf16x8 a8h = *(const bf16x8*)(vbh + off);
      bf16x8 a8l = *(const bf16x8*)(vbl + off);
      accA[ct] = mfma3(a8h, a8l, bAh, bAl, accA[ct]);
      accB[ct] = mfma3(a8h, a8l, bBh, bBl, accB[ct]);
    }
  }
  csA += __shfl_xor(csA, 16, 64);
  csA += __shfl_xor(csA, 32, 64);
  csB += __shfl_xor(csB, 16, 64);
  csB += __shfl_xor(csB, 32, 64);
  if (lane < 16) {
    csl[0][wave][lane] = csA;
    csl[1][wave][lane] = csB;
  }
  // ---- phase A combine + write (rows m0+col)
#pragma unroll
  for (int ct = 0; ct < 8; ++ct) accs[wave][ct][lane] = accA[ct];
  __syncthreads();
  {
    float inv = 1.0f / (1e-9f + csl[0][0][col] + csl[0][1][col] + csl[0][2][col] + csl[0][3][col]);
    const u16* xrh = xh + ((size_t)b * kN + m0 + col) * kC;
    const u16* xrl = xl + ((size_t)b * kN + m0 + col) * kC;
#pragma unroll
    for (int i = 0; i < 2; ++i) {
      int ct = wave * 2 + i;
      f32x4 a = accs[0][ct][lane];
      a += accs[1][ct][lane];
      a += accs[2][ct][lane];
      a += accs[3][ct][lane];
      bf16x4 xvh = *(const bf16x4*)(xrh + ct * 16 + 4 * g);
      bf16x4 xvl = *(const bf16x4*)(xrl + ct * 16 + 4 * g);
#pragma unroll
      for (int r = 0; r < 4; ++r) {
        float xv = bf2f((u16)xvh[r]) + bf2f((u16)xvl[r]);
        float y = xv - a[r] * inv;
        u16 hh, ll;
        split2(y, hh, ll);
        size_t idx = ((size_t)b * kN + m0 + col) * kC + ct * 16 + 4 * g + r;
        yth[idx] = hh;
        ytl[idx] = ll;
      }
    }
  }
  __syncthreads();
  // ---- phase B combine + write (rows m0+16+col)
#pragma unroll
  for (int ct = 0; ct < 8; ++ct) accs[wave][ct][lane] = accB[ct];
  __syncthreads();
  {
    float inv = 1.0f / (1e-9f + csl[1][0][col] + csl[1][1][col] + csl[1][2][col] + csl[1][3][col]);
    const u16* xrh = xh + ((size_t)b * kN + m0 + 16 + col) * kC;
    const u16* xrl = xl + ((size_t)b * kN + m0 + 16 + col) * kC;
#pragma unroll
    for (int i = 0; i < 2; ++i) {
      int ct = wave * 2 + i;
      f32x4 a = accs[0][ct][lane];
      a += accs[1][ct][lane];
      a += accs[2][ct][lane];
      a += accs[3][ct][lane];
      bf16x4 xvh = *(const bf16x4*)(xrh + ct * 16 + 4 * g);
      bf16x4 xvl = *(const bf16x4*)(xrl + ct * 16 + 4 * g);
#pragma unroll
      for (int r = 0; r < 4; ++r) {
        float xv = bf2f((u16)xvh[r]) + bf2f((u16)xvl[r]);
        float y = xv - a[r] * inv;
        u16 hh, ll;
        split2(y, hh, ll);
        size_t idx = ((size_t)b * kN + m0 + 16 + col) * kC + ct * 16 + 4 * g + r;
        yth[idx] = hh;
        ytl[idx] = ll;
      }
    }
  }
}

// ---------------- conv GEMM + fused BN partial sums (per-block, fp32):
// part[bid][c] = (sum over this block's 16 n of v, sum of v^2)
__global__ __launch_bounds__(256) void tconv_kernel(
    const u16* __restrict__ inh, const u16* __restrict__ inl,
    const u16* __restrict__ wh, const u16* __restrict__ wl,
    const float* __restrict__ bias, float* __restrict__ u,
    long ustride, long uoff, float* __restrict__ part) {
  int wave = threadIdx.x >> 6, lane = threadIdx.x & 63;
  int b = blockIdx.y;
  int n0 = blockIdx.x * 16;
  int col = lane & 15, g = lane >> 4;
  f32x4 acc[2] = {};
  const u16* xrh = inh + ((size_t)b * kN + n0 + col) * kC + g * 8;
  const u16* xrl = inl + ((size_t)b * kN + n0 + col) * kC + g * 8;
#pragma unroll
  for (int kk = 0; kk < 4; ++kk) {
    bf16x8 bh = *(const bf16x8*)(xrh + kk * 32);
    bf16x8 bl = *(const bf16x8*)(xrl + kk * 32);
#pragma unroll
    for (int i = 0; i < 2; ++i) {
      int ot = wave * 2 + i;
      bf16x8 ah = *(const bf16x8*)(wh + (size_t)(ot * 16 + col) * kC + kk * 32 + g * 8);
      bf16x8 al = *(const bf16x8*)(wl + (size_t)(ot * 16 + col) * kC + kk * 32 + g * 8);
      acc[i] = mfma3(ah, al, bh, bl, acc[i]);
    }
  }
  int bid = blockIdx.y * (kN / 16) + blockIdx.x;
#pragma unroll
  for (int i = 0; i < 2; ++i) {
    int ot = wave * 2 + i;
#pragma unroll
    for (int r = 0; r < 4; ++r) {
      int c = ot * 16 + 4 * g + r;
      float v = acc[i][r] + (bias ? bias[c] : 0.f);
      u[(size_t)b * ustride + uoff + (size_t)c * kN + n0 + col] = v;
      float s = v, q = v * v;
#pragma unroll
      for (int o = 1; o < 16; o <<= 1) {
        s += __shfl_xor(s, o, 64);
        q += __shfl_xor(q, o, 64);
      }
      if (col == 0) {
        part[((size_t)bid * kC + c) * 2 + 0] = s;
        part[((size_t)bid * kC + c) * 2 + 1] = q;
      }
    }
  }
}

// ---------------- BN finalize: reduce 1024 fp32 partials/channel in fp64
__global__ __launch_bounds__(256) void bn_fin_kernel(const float* __restrict__ part,
                                                     float* __restrict__ stat) {
  int c = blockIdx.x;  // 128 blocks
  __shared__ double rs[4], rss[4];
  double s = 0.0, ss = 0.0;
  for (int k = threadIdx.x; k < 1024; k += 256) {
    s += (double)part[((size_t)k * kC + c) * 2 + 0];
    ss += (double)part[((size_t)k * kC + c) * 2 + 1];
  }
#pragma unroll
  for (int o = 1; o < 64; o <<= 1) {
    s += __shfl_xor(s, o, 64);
    ss += __shfl_xor(ss, o, 64);
  }
  int wid = threadIdx.x >> 6, lane = threadIdx.x & 63;
  if (lane == 0) { rs[wid] = s; rss[wid] = ss; }
  __syncthreads();
  if (threadIdx.x == 0) {
    double S = rs[0] + rs[1] + rs[2] + rs[3];
    double SS = rss[0] + rss[1] + rss[2] + rss[3];
    double mean = S / (double)(kB * kN);
    double var = SS / (double)(kB * kN) - mean * mean;
    if (var < 0.0) var = 0.0;
    stat[c] = (float)mean;
    stat[kC + c] = rsqrtf((float)var + 1e-5f);
  }
}

// ---------------- fused bn_final + next-layer prep:
// y = relu(BN(u)) [+ h + e]; out = y; xh/xl = split(y + e)  (transpose via LDS)
__global__ __launch_bounds__(256) void bnprep_kernel(
    const float* __restrict__ u, long ustride, long uoff,
    const float* __restrict__ stat,
    const float* __restrict__ g, const float* __restrict__ bb,
    const float* __restrict__ h, long hstride, long hoff, int use_res,
    const float* __restrict__ xyz, const float* __restrict__ pw,
    const float* __restrict__ pb,
    float* __restrict__ out, long ostride, long ooff,
    u16* __restrict__ xh, u16* __restrict__ xl) {
  __shared__ float t[32][33];
  int n0 = blockIdx.x * 32, c0 = blockIdx.y * 32, b = blockIdx.z;
  int tx = threadIdx.x & 31, ty = threadIdx.x >> 5;  // 32 x 8
  const float* xp = xyz + ((size_t)b * kN + n0 + tx) * 3;
  float xv0 = xp[0], xv1 = xp[1], xv2 = xp[2];
#pragma unroll
  for (int i = 0; i < 4; ++i) {
    int c = c0 + ty + i * 8;
    float e = pw[c * 3 + 0] * xv0 + pw[c * 3 + 1] * xv1 + pw[c * 3 + 2] * xv2 + pb[c];
    float y = (u[(size_t)b * ustride + uoff + (size_t)c * kN + n0 + tx] - stat[c]) *
                  stat[kC + c] * g[c] + bb[c];
    y = fmaxf(y, 0.f);
    if (use_res) y += h[(size_t)b * hstride + hoff + (size_t)c * kN + n0 + tx] + e;
    out[(size_t)b * ostride + ooff + (size_t)c * kN + n0 + tx] = y;
    t[ty + i * 8][tx] = y + e;  // next layer's xa
  }
  __syncthreads();
#pragma unroll
  for (int i = 0; i < 4; ++i) {
    int n = n0 + ty + i * 8, c = c0 + tx;
    u16 hh, ll;
    split2(t[tx][ty + i * 8], hh, ll);
    size_t idx = ((size_t)b * kN + n) * kC + c;
    xh[idx] = hh;
    xl[idx] = ll;
  }
}

extern "C" void kernel_launch(void* const* d_in, const int* in_sizes, int n_in,
                              void* d_out, int out_size, void* d_ws, size_t ws_size,
                              hipStream_t stream) {
  const float* x = (const float*)d_in[0];
  const float* xyz = (const float*)d_in[1];
  const float* conv1_w = (const float*)d_in[2];
  const float* bn1_g = (const float*)d_in[3];
  const float* bn1_b = (const float*)d_in[4];
  const float* pos_w = (const float*)d_in[5];
  const float* pos_b = (const float*)d_in[6];
  const float* sa_wqk = (const float*)d_in[7];
  const float* sa_wv = (const float*)d_in[8];
  const float* sa_bv = (const float*)d_in[9];
  const float* sa_wt = (const float*)d_in[10];
  const float* sa_bt = (const float*)d_in[11];
  const float* sa_bng = (const float*)d_in[12];
  const float* sa_bnb = (const float*)d_in[13];
  float* out = (float*)d_out;
  char* ws = (char*)d_ws;
  const size_t MB = (size_t)1 << 20;

  const size_t NEED = 28 * MB;
  if (ws_size < NEED) {
    float val = 100.0f + (float)(ws_size >> 20);
    sentinel_kernel<<<dim3((out_size + 255) / 256), dim3(256), 0, stream>>>(out, val, out_size);
    return;
  }

  u16* xh = (u16*)(ws);                  // [0,4MB)
  u16* xl = (u16*)(ws + 4 * MB);         // [4,8MB)
  u16* yth = (u16*)(ws + 8 * MB);        // [8,12MB)
  u16* ytl = (u16*)(ws + 12 * MB);       // [12,16MB)
  u16* Vph = (u16*)(ws + 16 * MB);       // [16,20MB)  packed V hi
  u16* Vpl = (u16*)(ws + 20 * MB);       // [20,24MB)  packed V lo
  u16* Qh = (u16*)(ws + 24 * MB);        // [24,25MB)
  u16* Ql = (u16*)(ws + 25 * MB);        // [25,26MB)
  u16* wa = (u16*)(ws + 26 * MB);        // weight split arena [26MB, 26MB+784KB)
  size_t woff = 0;
  u16* c1h = wa + woff; woff += 16384;
  u16* c1l = wa + woff; woff += 16384;
  u16* qkh = wa + woff; woff += 5 * 32 * 128;
  u16* qkl = wa + woff; woff += 5 * 32 * 128;
  u16* wvh = wa + woff; woff += 5 * 128 * 128;
  u16* wvl = wa + woff; woff += 5 * 128 * 128;
  u16* wth = wa + woff; woff += 5 * 128 * 128;
  u16* wtl = wa + woff; woff += 5 * 128 * 128;
  float* stat = (float*)(ws + 26 * MB + 851968);        // 1 KB (after weight arena)
  // part (1MB) ALIASES rme (64KB): rme dead after pass2, part written by tconv after
  float* rme = (float*)(ws + 27 * MB);                  // [27MB, 27MB+64KB)
  float* part = (float*)(ws + 27 * MB);                 // [27MB, 28MB)

  dim3 blk(256);

  cvt_all_kernel<<<dim3(784), blk, 0, stream>>>(
      conv1_w, sa_wqk, sa_wv, sa_wt, c1h, c1l, qkh, qkl, wvh, wvl, wth, wtl);

  const long sbo = (long)kCO * kN;
  const long slice = (long)kC * kN;
  const long h0off = 4 * slice;  // h0 parked in layer-4 slice (dead after layer-0 reads)

  // ---- setup: conv1 + BN + relu -> h0; bnprep also emits layer-0 xa (h0 + emb)
  prep_kernel<<<dim3(kN / 32, kC / 32, kB), blk, 0, stream>>>(x, slice, 0, xh, xl);
  tconv_kernel<<<dim3(kN / 16, kB), blk, 0, stream>>>(
      xh, xl, c1h, c1l, nullptr, out, sbo, 0, part);
  bn_fin_kernel<<<dim3(kC), blk, 0, stream>>>(part, stat);
  bnprep_kernel<<<dim3(kN / 32, kC / 32, kB), blk, 0, stream>>>(
      out, sbo, 0, stat, bn1_g, bn1_b, nullptr, 0, 0, 0, xyz, pos_w, pos_b,
      out, sbo, h0off, xh, xl);

  long hoff = h0off;
  for (int i = 0; i < kL; ++i) {
    long uoff = (long)i * slice;  // layer-i pre-BN u lives in out slice i (in-place BN)
    qv_kernel<<<dim3(kN / 16, kB), dim3(320), 0, stream>>>(
        xh, xl, qkh + (size_t)i * kD * kC, qkl + (size_t)i * kD * kC,
        wvh + (size_t)i * kC * kC, wvl + (size_t)i * kC * kC,
        sa_bv + (size_t)i * kC, Qh, Ql, Vph, Vpl);
    pass1_kernel<<<dim3(kN / 32, kB), blk, 0, stream>>>(Qh, Ql, rme);
    pass2_kernel<<<dim3(kN / 32, kB), blk, 0, stream>>>(
        Qh, Ql, Vph, Vpl, rme, xh, xl, yth, ytl);
    tconv_kernel<<<dim3(kN / 16, kB), blk, 0, stream>>>(
        yth, ytl, wth + (size_t)i * kC * kC, wtl + (size_t)i * kC * kC,
        sa_bt + (size_t)i * kC, out, sbo, uoff, part);
    bn_fin_kernel<<<dim3(kC), blk, 0, stream>>>(part, stat);
    bnprep_kernel<<<dim3(kN / 32, kC / 32, kB), blk, 0, stream>>>(
        out, sbo, uoff, stat, sa_bng + (size_t)i * kC, sa_bnb + (size_t)i * kC,
        out, sbo, hoff, 1, xyz, pos_w, pos_b, out, sbo, uoff, xh, xl);
    hoff = uoff;
  }
}

// Round 20
// 798.023 us; speedup vs baseline: 1.2702x; 1.0174x over previous
//
#include <hip/hip_runtime.h>

#define kB 4
#define kC 128
#define kN 4096
#define kD 32
#define kL 5
#define kCO 640
#define kL2E 1.4426950408889634f

typedef float f32x4 __attribute__((ext_vector_type(4)));
typedef short bf16x4 __attribute__((ext_vector_type(4)));
typedef short bf16x8 __attribute__((ext_vector_type(8)));
typedef unsigned u32;
typedef u32 u32x4 __attribute__((ext_vector_type(4)));
typedef unsigned short u16;

__device__ __forceinline__ float bf2f(u16 u) {
  unsigned v = ((unsigned)u) << 16;
  return __builtin_bit_cast(float, v);
}
__device__ __forceinline__ u16 f2bf(float f) {
  unsigned u = __builtin_bit_cast(unsigned, f);
  u += 0x7fffu + ((u >> 16) & 1u);
  return (u16)(u >> 16);
}
__device__ __forceinline__ void split2(float v, u16& hi, u16& lo) {
  hi = f2bf(v);
  lo = f2bf(v - bf2f(hi));
}
// raw v_exp_f32 / v_log_f32 (libm versions add ~10 fixup ops without -ffast-math)
__device__ __forceinline__ float fexp2(float x) {
#if __has_builtin(__builtin_amdgcn_exp2f)
  return __builtin_amdgcn_exp2f(x);
#else
  return exp2f(x);
#endif
}
__device__ __forceinline__ float flog2(float x) {
#if __has_builtin(__builtin_amdgcn_logf)
  return __builtin_amdgcn_logf(x);
#else
  return log2f(x);
#endif
}
// single-exp branchless online-softmax update (BIT-EXACT vs 2-exp form):
// exp2(-|d|) == exp2(d) for d<=0, == exp2(-d) for d>0.
__device__ __forceinline__ void online_upd(float& mx, float& sm, float s) {
  float d = s - mx;
  float e = fexp2(-fabsf(d) * kL2E);
  bool up = s > mx;
  sm = (up ? 1.f : sm) + e * (up ? sm : 1.f);
  mx = fmaxf(mx, s);
}
// merge (M,S) with (Mo,So): single-exp branchless, bit-exact vs 2-exp form
__device__ __forceinline__ void online_merge(float& M, float& S, float Mo, float So) {
  float d = Mo - M;
  float e = fexp2(-fabsf(d) * kL2E);
  bool up = Mo > M;
  S = (up ? So : S) + e * (up ? S : So);
  M = fmaxf(M, Mo);
}
// pack pair (a,b) -> hi-word (trunc bf16s) and lo-word (trunc of residuals).
__device__ __forceinline__ u32 pkhalves(u32 a, u32 b) {
#if __has_builtin(__builtin_amdgcn_perm)
  return __builtin_amdgcn_perm(b, a, 0x07060302u);
#else
  return (a >> 16) | (b & 0xffff0000u);
#endif
}
__device__ __forceinline__ void splitpair(float a, float b, u32& hw, u32& lw) {
  u32 ua = __builtin_bit_cast(u32, a), ub = __builtin_bit_cast(u32, b);
  hw = pkhalves(ua, ub);
  float la = a - __builtin_bit_cast(float, ua & 0xffff0000u);
  float lb = b - __builtin_bit_cast(float, ub & 0xffff0000u);
  lw = pkhalves(__builtin_bit_cast(u32, la), __builtin_bit_cast(u32, lb));
}
// s += A*B with split operands: ah*bh + ah*bl + al*bh (drops al*bl, ~2^-16 rel)
__device__ __forceinline__ f32x4 mfma3(bf16x8 ah, bf16x8 al, bf16x8 bh, bf16x8 bl, f32x4 c) {
  c = __builtin_amdgcn_mfma_f32_16x16x32_bf16(ah, bh, c, 0, 0, 0);
  c = __builtin_amdgcn_mfma_f32_16x16x32_bf16(ah, bl, c, 0, 0, 0);
  c = __builtin_amdgcn_mfma_f32_16x16x32_bf16(al, bh, c, 0, 0, 0);
  return c;
}

// ---------------- sentinel (ws too small): encodes ws MB into output
__global__ void sentinel_kernel(float* out, float val, int total) {
  int i = blockIdx.x * 256 + threadIdx.x;
  if (i < total) out[i] = val;
}

// ---------------- split ALL fp32 weight arrays -> bf16 hi/lo arenas (one launch)
__global__ void cvt_all_kernel(const float* __restrict__ s0, const float* __restrict__ s1,
                               const float* __restrict__ s2, const float* __restrict__ s3,
                               u16* h0, u16* l0, u16* h1, u16* l1,
                               u16* h2, u16* l2, u16* h3, u16* l3) {
  int i = blockIdx.x * 256 + threadIdx.x;
  const float* s;
  u16 *dh, *dl;
  int off;
  if (i < 16384) { s = s0; dh = h0; dl = l0; off = i; }
  else if (i < 36864) { s = s1; dh = h1; dl = l1; off = i - 16384; }
  else if (i < 118784) { s = s2; dh = h2; dl = l2; off = i - 36864; }
  else if (i < 200704) { s = s3; dh = h3; dl = l3; off = i - 118784; }
  else return;
  u16 h, l;
  split2(s[off], h, l);
  dh[off] = h;
  dl[off] = l;
}

// ---------------- xh/xl[b][n][c] = split(h[b][c][n])   (transpose + split; setup only)
__global__ __launch_bounds__(256) void prep_kernel(
    const float* __restrict__ h, long hstride, long hoff,
    u16* __restrict__ xh, u16* __restrict__ xl) {
  __shared__ float t[32][33];
  int n0 = blockIdx.x * 32, c0 = blockIdx.y * 32, b = blockIdx.z;
  int tx = threadIdx.x & 31, ty = threadIdx.x >> 5;  // 32 x 8
#pragma unroll
  for (int i = 0; i < 4; ++i) {
    int c = c0 + ty + i * 8;
    t[ty + i * 8][tx] = h[(size_t)b * hstride + hoff + (size_t)c * kN + n0 + tx];
  }
  __syncthreads();
#pragma unroll
  for (int i = 0; i < 4; ++i) {
    int n = n0 + ty + i * 8, c = c0 + tx;
    u16 hh, ll;
    split2(t[tx][ty + i * 8], hh, ll);
    size_t idx = ((size_t)b * kN + n) * kC + c;
    xh[idx] = hh;
    xl[idx] = ll;
  }
}

// ---------------- QV GEMM: 5 waves x 2 tiles, 16 n-cols per block.
// V written in FRAGMENT-PACKED layout: Vp[b][nt=n/32][ct=c/16][lane][8 bf16],
// lane=(g<<4)|col holds V[ct*16+col][nt*32+4g..+3] (p=0) and [nt*32+16+4g..+3] (p=1).
__global__ __launch_bounds__(320) void qv_kernel(
    const u16* __restrict__ xh, const u16* __restrict__ xl,
    const u16* __restrict__ wqkh, const u16* __restrict__ wqkl,
    const u16* __restrict__ wvh, const u16* __restrict__ wvl,
    const float* __restrict__ bv,
    u16* __restrict__ Qh, u16* __restrict__ Ql,
    u16* __restrict__ Vph, u16* __restrict__ Vpl) {
  __shared__ float vt[4][2][16][17];
  int wave = threadIdx.x >> 6, lane = threadIdx.x & 63;  // wave 0..4
  int b = blockIdx.y;
  int n0 = blockIdx.x * 16;
  int col = lane & 15, g = lane >> 4;
  f32x4 acc[2] = {};
  const u16* xrh = xh + ((size_t)b * kN + n0 + col) * kC + g * 8;
  const u16* xrl = xl + ((size_t)b * kN + n0 + col) * kC + g * 8;
#pragma unroll
  for (int kk = 0; kk < 4; ++kk) {
    bf16x8 bh = *(const bf16x8*)(xrh + kk * 32);
    bf16x8 bl = *(const bf16x8*)(xrl + kk * 32);
#pragma unroll
    for (int i = 0; i < 2; ++i) {
      int ot = wave * 2 + i;
      size_t wi = (ot < 2) ? ((size_t)(ot * 16 + col) * kC) : ((size_t)((ot - 2) * 16 + col) * kC);
      const u16* wsh = (ot < 2) ? (wqkh + wi) : (wvh + wi);
      const u16* wsl = (ot < 2) ? (wqkl + wi) : (wvl + wi);
      bf16x8 ah = *(const bf16x8*)(wsh + kk * 32 + g * 8);
      bf16x8 al = *(const bf16x8*)(wsl + kk * 32 + g * 8);
      acc[i] = mfma3(ah, al, bh, bl, acc[i]);
    }
  }
  if (wave > 0) {
#pragma unroll
    for (int i = 0; i < 2; ++i) {
      int ct = wave * 2 + i - 2;
#pragma unroll
      for (int r = 0; r < 4; ++r)
        vt[wave - 1][i][4 * g + r][col] = acc[i][r] + bv[ct * 16 + 4 * g + r];
    }
  }
  __syncthreads();
  if (wave == 0) {
#pragma unroll
    for (int i = 0; i < 2; ++i) {
#pragma unroll
      for (int r = 0; r < 4; ++r) {
        int d = i * 16 + 4 * g + r;
        u16 hh, ll;
        split2(acc[i][r], hh, ll);
        size_t idx = ((size_t)b * kN + n0 + col) * kD + d;
        Qh[idx] = hh;
        Ql[idx] = ll;
      }
    }
  } else {
    int nt = n0 >> 5, p = (n0 >> 4) & 1;
#pragma unroll
    for (int i = 0; i < 2; ++i) {
      int ct = wave * 2 + i - 2;
      bf16x4 vh4, vl4;
#pragma unroll
      for (int j = 0; j < 4; ++j) {
        float v = vt[wave - 1][i][col][4 * g + j];
        u16 hh, ll;
        split2(v, hh, ll);
        vh4[j] = (short)hh;
        vl4[j] = (short)ll;
      }
      size_t base = ((((size_t)b * (kN / 32) + nt) * 8 + ct) * 64 + lane) * 8 + p * 4;
      *(bf16x4*)(Vph + base) = vh4;
      *(bf16x4*)(Vpl + base) = vl4;
    }
  }
}

// ---------------- pass1 v4: block n-32 (2 a-frags/wave), 4 waves split m; LDS merge.
// Single-exp branchless online updates (bit-exact). Stores e' = max*log2e + log2(sum).
__global__ __launch_bounds__(256) void pass1_kernel(
    const u16* __restrict__ Qh, const u16* __restrict__ Ql,
    float* __restrict__ rme) {
  __shared__ float mxs[4][32], sms[4][32];
  int wave = threadIdx.x >> 6, lane = threadIdx.x & 63;
  int b = blockIdx.y;
  int n0 = blockIdx.x * 32;
  int col = lane & 15, g = lane >> 4;
  const u16* qbh = Qh + (size_t)b * kN * kD;
  const u16* qbl = Ql + (size_t)b * kN * kD;
  bf16x8 ah0 = *(const bf16x8*)(qbh + (size_t)(n0 + col) * kD + g * 8);
  bf16x8 al0 = *(const bf16x8*)(qbl + (size_t)(n0 + col) * kD + g * 8);
  bf16x8 ah1 = *(const bf16x8*)(qbh + (size_t)(n0 + 16 + col) * kD + g * 8);
  bf16x8 al1 = *(const bf16x8*)(qbl + (size_t)(n0 + 16 + col) * kD + g * 8);
  float mx[8], sm[8];
#pragma unroll
  for (int r = 0; r < 8; ++r) { mx[r] = -3.0e38f; sm[r] = 0.f; }
#pragma unroll 1
  for (int m0 = wave * 16; m0 < kN; m0 += 64) {
    bf16x8 bh = *(const bf16x8*)(qbh + (size_t)(m0 + col) * kD + g * 8);
    bf16x8 bl = *(const bf16x8*)(qbl + (size_t)(m0 + col) * kD + g * 8);
    f32x4 s0 = {}, s1 = {};
    s0 = mfma3(ah0, al0, bh, bl, s0);
    s1 = mfma3(ah1, al1, bh, bl, s1);
#pragma unroll
    for (int r = 0; r < 4; ++r) {
      online_upd(mx[r], sm[r], s0[r]);
      online_upd(mx[r + 4], sm[r + 4], s1[r]);
    }
  }
#pragma unroll
  for (int o = 1; o < 16; o <<= 1) {
#pragma unroll
    for (int r = 0; r < 8; ++r) {
      float Mo = __shfl_xor(mx[r], o, 64);
      float So = __shfl_xor(sm[r], o, 64);
      online_merge(mx[r], sm[r], Mo, So);
    }
  }
  if (col == 0) {
#pragma unroll
    for (int r = 0; r < 4; ++r) {
      mxs[wave][4 * g + r] = mx[r];
      sms[wave][4 * g + r] = sm[r];
      mxs[wave][16 + 4 * g + r] = mx[r + 4];
      sms[wave][16 + 4 * g + r] = sm[r + 4];
    }
  }
  __syncthreads();
  if (threadIdx.x < 32) {
    int t = threadIdx.x;
    float M = mxs[0][t], S = sms[0][t];
#pragma unroll
    for (int w = 1; w < 4; ++w) online_merge(M, S, mxs[w][t], sms[w][t]);
    rme[(size_t)b * kN + n0 + t] = M * kL2E + flog2(S);
  }
}

// ---------------- pass2 v10: block m-32, 256 thr, 2 m-frags/wave (V register-reuse),
// p = exp2(s*log2e - e'), v_perm packing. No in-loop barriers; LDS end-combine.
__global__ __launch_bounds__(256) void pass2_kernel(
    const u16* __restrict__ Qh, const u16* __restrict__ Ql,
    const u16* __restrict__ Vph, const u16* __restrict__ Vpl,
    const float* __restrict__ rme,
    const u16* __restrict__ xh, const u16* __restrict__ xl,
    u16* __restrict__ yth, u16* __restrict__ ytl) {
  __shared__ f32x4 accs[4][8][64];
  __shared__ float csl[2][4][16];
  int wave = threadIdx.x >> 6, lane = threadIdx.x & 63;
  int b = blockIdx.y;
  int m0 = blockIdx.x * 32;
  int col = lane & 15, g = lane >> 4;
  const u16* qbh = Qh + (size_t)b * kN * kD;
  const u16* qbl = Ql + (size_t)b * kN * kD;
  const float* rmb = rme + (size_t)b * kN;
  bf16x8 bmh0 = *(const bf16x8*)(qbh + (size_t)(m0 + col) * kD + g * 8);
  bf16x8 bml0 = *(const bf16x8*)(qbl + (size_t)(m0 + col) * kD + g * 8);
  bf16x8 bmh1 = *(const bf16x8*)(qbh + (size_t)(m0 + 16 + col) * kD + g * 8);
  bf16x8 bml1 = *(const bf16x8*)(qbl + (size_t)(m0 + 16 + col) * kD + g * 8);
  const u16* vbh = Vph + (size_t)b * (kN / 32) * 4096;
  const u16* vbl = Vpl + (size_t)b * (kN / 32) * 4096;
  f32x4 accA[8] = {}, accB[8] = {};
  float csA = 0.f, csB = 0.f;
#pragma unroll 1
  for (int nn = wave * 32; nn < kN; nn += 128) {
    bf16x8 ah0 = *(const bf16x8*)(qbh + (size_t)(nn + col) * kD + g * 8);
    bf16x8 al0 = *(const bf16x8*)(qbl + (size_t)(nn + col) * kD + g * 8);
    bf16x8 ah1 = *(const bf16x8*)(qbh + (size_t)(nn + 16 + col) * kD + g * 8);
    bf16x8 al1 = *(const bf16x8*)(qbl + (size_t)(nn + 16 + col) * kD + g * 8);
    f32x4 sA0 = {}, sA1 = {}, sB0 = {}, sB1 = {};
    sA0 = mfma3(ah0, al0, bmh0, bml0, sA0);
    sA1 = mfma3(ah1, al1, bmh0, bml0, sA1);
    sB0 = mfma3(ah0, al0, bmh1, bml1, sB0);
    sB1 = mfma3(ah1, al1, bmh1, bml1, sB1);
    float pA[8], pB[8];
#pragma unroll
    for (int r = 0; r < 4; ++r) {
      float e0 = rmb[nn + 4 * g + r];
      float e1 = rmb[nn + 16 + 4 * g + r];
      pA[r] = fexp2(sA0[r] * kL2E - e0);
      pA[r + 4] = fexp2(sA1[r] * kL2E - e1);
      pB[r] = fexp2(sB0[r] * kL2E - e0);
      pB[r + 4] = fexp2(sB1[r] * kL2E - e1);
      csA += pA[r] + pA[r + 4];
      csB += pB[r] + pB[r + 4];
    }
    u32x4 Ahw, Alw, Bhw, Blw;
#pragma unroll
    for (int k2 = 0; k2 < 4; ++k2) {
      u32 h0, l0, h1, l1;
      splitpair(pA[2 * k2], pA[2 * k2 + 1], h0, l0);
      splitpair(pB[2 * k2], pB[2 * k2 + 1], h1, l1);
      Ahw[k2] = h0; Alw[k2] = l0;
      Bhw[k2] = h1; Blw[k2] = l1;
    }
    bf16x8 bAh = __builtin_bit_cast(bf16x8, Ahw);
    bf16x8 bAl = __builtin_bit_cast(bf16x8, Alw);
    bf16x8 bBh = __builtin_bit_cast(bf16x8, Bhw);
    bf16x8 bBl = __builtin_bit_cast(bf16x8, Blw);
    size_t vtile = (size_t)(nn >> 5) * 4096;
#pragma unroll
    for (int ct = 0; ct < 8; ++ct) {
      size_t off = vtile + ((size_t)ct * 64 + lane) * 8;
      bf16x8 a8h = *(const bf16x8*)(vbh + off);
      bf16x8 a8l = *(const bf16x8*)(vbl + off);
      accA[ct] = mfma3(a8h, a8l, bAh, bAl, accA[ct]);
      accB[ct] = mfma3(a8h, a8l, bBh, bBl, accB[ct]);
    }
  }
  csA += __shfl_xor(csA, 16, 64);
  csA += __shfl_xor(csA, 32, 64);
  csB += __shfl_xor(csB, 16, 64);
  csB += __shfl_xor(csB, 32, 64);
  if (lane < 16) {
    csl[0][wave][lane] = csA;
    csl[1][wave][lane] = csB;
  }
  // ---- phase A combine + write (rows m0+col)
#pragma unroll
  for (int ct = 0; ct < 8; ++ct) accs[wave][ct][lane] = accA[ct];
  __syncthreads();
  {
    float inv = 1.0f / (1e-9f + csl[0][0][col] + csl[0][1][col] + csl[0][2][col] + csl[0][3][col]);
    const u16* xrh = xh + ((size_t)b * kN + m0 + col) * kC;
    const u16* xrl = xl + ((size_t)b * kN + m0 + col) * kC;
#pragma unroll
    for (int i = 0; i < 2; ++i) {
      int ct = wave * 2 + i;
      f32x4 a = accs[0][ct][lane];
      a += accs[1][ct][lane];
      a += accs[2][ct][lane];
      a += accs[3][ct][lane];
      bf16x4 xvh = *(const bf16x4*)(xrh + ct * 16 + 4 * g);
      bf16x4 xvl = *(const bf16x4*)(xrl + ct * 16 + 4 * g);
#pragma unroll
      for (int r = 0; r < 4; ++r) {
        float xv = bf2f((u16)xvh[r]) + bf2f((u16)xvl[r]);
        float y = xv - a[r] * inv;
        u16 hh, ll;
        split2(y, hh, ll);
        size_t idx = ((size_t)b * kN + m0 + col) * kC + ct * 16 + 4 * g + r;
        yth[idx] = hh;
        ytl[idx] = ll;
      }
    }
  }
  __syncthreads();
  // ---- phase B combine + write (rows m0+16+col)
#pragma unroll
  for (int ct = 0; ct < 8; ++ct) accs[wave][ct][lane] = accB[ct];
  __syncthreads();
  {
    float inv = 1.0f / (1e-9f + csl[1][0][col] + csl[1][1][col] + csl[1][2][col] + csl[1][3][col]);
    const u16* xrh = xh + ((size_t)b * kN + m0 + 16 + col) * kC;
    const u16* xrl = xl + ((size_t)b * kN + m0 + 16 + col) * kC;
#pragma unroll
    for (int i = 0; i < 2; ++i) {
      int ct = wave * 2 + i;
      f32x4 a = accs[0][ct][lane];
      a += accs[1][ct][lane];
      a += accs[2][ct][lane];
      a += accs[3][ct][lane];
      bf16x4 xvh = *(const bf16x4*)(xrh + ct * 16 + 4 * g);
      bf16x4 xvl = *(const bf16x4*)(xrl + ct * 16 + 4 * g);
#pragma unroll
      for (int r = 0; r < 4; ++r) {
        float xv = bf2f((u16)xvh[r]) + bf2f((u16)xvl[r]);
        float y = xv - a[r] * inv;
        u16 hh, ll;
        split2(y, hh, ll);
        size_t idx = ((size_t)b * kN + m0 + 16 + col) * kC + ct * 16 + 4 * g + r;
        yth[idx] = hh;
        ytl[idx] = ll;
      }
    }
  }
}

// ---------------- conv GEMM + fused BN partial sums (per-block, fp32)
__global__ __launch_bounds__(256) void tconv_kernel(
    const u16* __restrict__ inh, const u16* __restrict__ inl,
    const u16* __restrict__ wh, const u16* __restrict__ wl,
    const float* __restrict__ bias, float* __restrict__ u,
    long ustride, long uoff, float* __restrict__ part) {
  int wave = threadIdx.x >> 6, lane = threadIdx.x & 63;
  int b = blockIdx.y;
  int n0 = blockIdx.x * 16;
  int col = lane & 15, g = lane >> 4;
  f32x4 acc[2] = {};
  const u16* xrh = inh + ((size_t)b * kN + n0 + col) * kC + g * 8;
  const u16* xrl = inl + ((size_t)b * kN + n0 + col) * kC + g * 8;
#pragma unroll
  for (int kk = 0; kk < 4; ++kk) {
    bf16x8 bh = *(const bf16x8*)(xrh + kk * 32);
    bf16x8 bl = *(const bf16x8*)(xrl + kk * 32);
#pragma unroll
    for (int i = 0; i < 2; ++i) {
      int ot = wave * 2 + i;
      bf16x8 ah = *(const bf16x8*)(wh + (size_t)(ot * 16 + col) * kC + kk * 32 + g * 8);
      bf16x8 al = *(const bf16x8*)(wl + (size_t)(ot * 16 + col) * kC + kk * 32 + g * 8);
      acc[i] = mfma3(ah, al, bh, bl, acc[i]);
    }
  }
  int bid = blockIdx.y * (kN / 16) + blockIdx.x;
#pragma unroll
  for (int i = 0; i < 2; ++i) {
    int ot = wave * 2 + i;
#pragma unroll
    for (int r = 0; r < 4; ++r) {
      int c = ot * 16 + 4 * g + r;
      float v = acc[i][r] + (bias ? bias[c] : 0.f);
      u[(size_t)b * ustride + uoff + (size_t)c * kN + n0 + col] = v;
      float s = v, q = v * v;
#pragma unroll
      for (int o = 1; o < 16; o <<= 1) {
        s += __shfl_xor(s, o, 64);
        q += __shfl_xor(q, o, 64);
      }
      if (col == 0) {
        part[((size_t)bid * kC + c) * 2 + 0] = s;
        part[((size_t)bid * kC + c) * 2 + 1] = q;
      }
    }
  }
}

// ---------------- BN finalize: reduce 1024 fp32 partials/channel in fp64
__global__ __launch_bounds__(256) void bn_fin_kernel(const float* __restrict__ part,
                                                     float* __restrict__ stat) {
  int c = blockIdx.x;  // 128 blocks
  __shared__ double rs[4], rss[4];
  double s = 0.0, ss = 0.0;
  for (int k = threadIdx.x; k < 1024; k += 256) {
    s += (double)part[((size_t)k * kC + c) * 2 + 0];
    ss += (double)part[((size_t)k * kC + c) * 2 + 1];
  }
#pragma unroll
  for (int o = 1; o < 64; o <<= 1) {
    s += __shfl_xor(s, o, 64);
    ss += __shfl_xor(ss, o, 64);
  }
  int wid = threadIdx.x >> 6, lane = threadIdx.x & 63;
  if (lane == 0) { rs[wid] = s; rss[wid] = ss; }
  __syncthreads();
  if (threadIdx.x == 0) {
    double S = rs[0] + rs[1] + rs[2] + rs[3];
    double SS = rss[0] + rss[1] + rss[2] + rss[3];
    double mean = S / (double)(kB * kN);
    double var = SS / (double)(kB * kN) - mean * mean;
    if (var < 0.0) var = 0.0;
    stat[c] = (float)mean;
    stat[kC + c] = rsqrtf((float)var + 1e-5f);
  }
}

// ---------------- fused bn_final + next-layer prep
__global__ __launch_bounds__(256) void bnprep_kernel(
    const float* __restrict__ u, long ustride, long uoff,
    const float* __restrict__ stat,
    const float* __restrict__ g, const float* __restrict__ bb,
    const float* __restrict__ h, long hstride, long hoff, int use_res,
    const float* __restrict__ xyz, const float* __restrict__ pw,
    const float* __restrict__ pb,
    float* __restrict__ out, long ostride, long ooff,
    u16* __restrict__ xh, u16* __restrict__ xl) {
  __shared__ float t[32][33];
  int n0 = blockIdx.x * 32, c0 = blockIdx.y * 32, b = blockIdx.z;
  int tx = threadIdx.x & 31, ty = threadIdx.x >> 5;  // 32 x 8
  const float* xp = xyz + ((size_t)b * kN + n0 + tx) * 3;
  float xv0 = xp[0], xv1 = xp[1], xv2 = xp[2];
#pragma unroll
  for (int i = 0; i < 4; ++i) {
    int c = c0 + ty + i * 8;
    float e = pw[c * 3 + 0] * xv0 + pw[c * 3 + 1] * xv1 + pw[c * 3 + 2] * xv2 + pb[c];
    float y = (u[(size_t)b * ustride + uoff + (size_t)c * kN + n0 + tx] - stat[c]) *
                  stat[kC + c] * g[c] + bb[c];
    y = fmaxf(y, 0.f);
    if (use_res) y += h[(size_t)b * hstride + hoff + (size_t)c * kN + n0 + tx] + e;
    out[(size_t)b * ostride + ooff + (size_t)c * kN + n0 + tx] = y;
    t[ty + i * 8][tx] = y + e;  // next layer's xa
  }
  __syncthreads();
#pragma unroll
  for (int i = 0; i < 4; ++i) {
    int n = n0 + ty + i * 8, c = c0 + tx;
    u16 hh, ll;
    split2(t[tx][ty + i * 8], hh, ll);
    size_t idx = ((size_t)b * kN + n) * kC + c;
    xh[idx] = hh;
    xl[idx] = ll;
  }
}

extern "C" void kernel_launch(void* const* d_in, const int* in_sizes, int n_in,
                              void* d_out, int out_size, void* d_ws, size_t ws_size,
                              hipStream_t stream) {
  const float* x = (const float*)d_in[0];
  const float* xyz = (const float*)d_in[1];
  const float* conv1_w = (const float*)d_in[2];
  const float* bn1_g = (const float*)d_in[3];
  const float* bn1_b = (const float*)d_in[4];
  const float* pos_w = (const float*)d_in[5];
  const float* pos_b = (const float*)d_in[6];
  const float* sa_wqk = (const float*)d_in[7];
  const float* sa_wv = (const float*)d_in[8];
  const float* sa_bv = (const float*)d_in[9];
  const float* sa_wt = (const float*)d_in[10];
  const float* sa_bt = (const float*)d_in[11];
  const float* sa_bng = (const float*)d_in[12];
  const float* sa_bnb = (const float*)d_in[13];
  float* out = (float*)d_out;
  char* ws = (char*)d_ws;
  const size_t MB = (size_t)1 << 20;

  const size_t NEED = 28 * MB;
  if (ws_size < NEED) {
    float val = 100.0f + (float)(ws_size >> 20);
    sentinel_kernel<<<dim3((out_size + 255) / 256), dim3(256), 0, stream>>>(out, val, out_size);
    return;
  }

  u16* xh = (u16*)(ws);                  // [0,4MB)
  u16* xl = (u16*)(ws + 4 * MB);         // [4,8MB)
  u16* yth = (u16*)(ws + 8 * MB);        // [8,12MB)
  u16* ytl = (u16*)(ws + 12 * MB);       // [12,16MB)
  u16* Vph = (u16*)(ws + 16 * MB);       // [16,20MB)  packed V hi
  u16* Vpl = (u16*)(ws + 20 * MB);       // [20,24MB)  packed V lo
  u16* Qh = (u16*)(ws + 24 * MB);        // [24,25MB)
  u16* Ql = (u16*)(ws + 25 * MB);        // [25,26MB)
  u16* wa = (u16*)(ws + 26 * MB);        // weight split arena [26MB, 26MB+784KB)
  size_t woff = 0;
  u16* c1h = wa + woff; woff += 16384;
  u16* c1l = wa + woff; woff += 16384;
  u16* qkh = wa + woff; woff += 5 * 32 * 128;
  u16* qkl = wa + woff; woff += 5 * 32 * 128;
  u16* wvh = wa + woff; woff += 5 * 128 * 128;
  u16* wvl = wa + woff; woff += 5 * 128 * 128;
  u16* wth = wa + woff; woff += 5 * 128 * 128;
  u16* wtl = wa + woff; woff += 5 * 128 * 128;
  float* stat = (float*)(ws + 26 * MB + 851968);        // 1 KB (after weight arena)
  // part (1MB) ALIASES rme (64KB): rme dead after pass2, part written by tconv after
  float* rme = (float*)(ws + 27 * MB);                  // [27MB, 27MB+64KB)
  float* part = (float*)(ws + 27 * MB);                 // [27MB, 28MB)

  dim3 blk(256);

  cvt_all_kernel<<<dim3(784), blk, 0, stream>>>(
      conv1_w, sa_wqk, sa_wv, sa_wt, c1h, c1l, qkh, qkl, wvh, wvl, wth, wtl);

  const long sbo = (long)kCO * kN;
  const long slice = (long)kC * kN;
  const long h0off = 4 * slice;  // h0 parked in layer-4 slice (dead after layer-0 reads)

  // ---- setup: conv1 + BN + relu -> h0; bnprep also emits layer-0 xa (h0 + emb)
  prep_kernel<<<dim3(kN / 32, kC / 32, kB), blk, 0, stream>>>(x, slice, 0, xh, xl);
  tconv_kernel<<<dim3(kN / 16, kB), blk, 0, stream>>>(
      xh, xl, c1h, c1l, nullptr, out, sbo, 0, part);
  bn_fin_kernel<<<dim3(kC), blk, 0, stream>>>(part, stat);
  bnprep_kernel<<<dim3(kN / 32, kC / 32, kB), blk, 0, stream>>>(
      out, sbo, 0, stat, bn1_g, bn1_b, nullptr, 0, 0, 0, xyz, pos_w, pos_b,
      out, sbo, h0off, xh, xl);

  long hoff = h0off;
  for (int i = 0; i < kL; ++i) {
    long uoff = (long)i * slice;  // layer-i pre-BN u lives in out slice i (in-place BN)
    qv_kernel<<<dim3(kN / 16, kB), dim3(320), 0, stream>>>(
        xh, xl, qkh + (size_t)i * kD * kC, qkl + (size_t)i * kD * kC,
        wvh + (size_t)i * kC * kC, wvl + (size_t)i * kC * kC,
        sa_bv + (size_t)i * kC, Qh, Ql, Vph, Vpl);
    pass1_kernel<<<dim3(kN / 32, kB), blk, 0, stream>>>(Qh, Ql, rme);
    pass2_kernel<<<dim3(kN / 32, kB), blk, 0, stream>>>(
        Qh, Ql, Vph, Vpl, rme, xh, xl, yth, ytl);
    tconv_kernel<<<dim3(kN / 16, kB), blk, 0, stream>>>(
        yth, ytl, wth + (size_t)i * kC * kC, wtl + (size_t)i * kC * kC,
        sa_bt + (size_t)i * kC, out, sbo, uoff, part);
    bn_fin_kernel<<<dim3(kC), blk, 0, stream>>>(part, stat);
    bnprep_kernel<<<dim3(kN / 32, kC / 32, kB), blk, 0, stream>>>(
        out, sbo, uoff, stat, sa_bng + (size_t)i * kC, sa_bnb + (size_t)i * kC,
        out, sbo, hoff, 1, xyz, pos_w, pos_b, out, sbo, uoff, xh, xl);
    hoff = uoff;
  }
}

// Round 21
// 738.245 us; speedup vs baseline: 1.3731x; 1.0810x over previous
//
#include <hip/hip_runtime.h>

#define kB 4
#define kC 128
#define kN 4096
#define kD 32
#define kL 5
#define kCO 640
#define kL2E 1.4426950408889634f

typedef float f32x4 __attribute__((ext_vector_type(4)));
typedef short bf16x4 __attribute__((ext_vector_type(4)));
typedef short bf16x8 __attribute__((ext_vector_type(8)));
typedef unsigned u32;
typedef u32 u32x4 __attribute__((ext_vector_type(4)));
typedef unsigned short u16;

__device__ __forceinline__ float bf2f(u16 u) {
  unsigned v = ((unsigned)u) << 16;
  return __builtin_bit_cast(float, v);
}
__device__ __forceinline__ u16 f2bf(float f) {
  unsigned u = __builtin_bit_cast(unsigned, f);
  u += 0x7fffu + ((u >> 16) & 1u);
  return (u16)(u >> 16);
}
__device__ __forceinline__ void split2(float v, u16& hi, u16& lo) {
  hi = f2bf(v);
  lo = f2bf(v - bf2f(hi));
}
__device__ __forceinline__ float fexp2(float x) {
#if __has_builtin(__builtin_amdgcn_exp2f)
  return __builtin_amdgcn_exp2f(x);
#else
  return exp2f(x);
#endif
}
__device__ __forceinline__ float flog2(float x) {
#if __has_builtin(__builtin_amdgcn_logf)
  return __builtin_amdgcn_logf(x);
#else
  return log2f(x);
#endif
}
// single-exp branchless online-softmax update (bit-exact vs 2-exp form)
__device__ __forceinline__ void online_upd(float& mx, float& sm, float s) {
  float d = s - mx;
  float e = fexp2(-fabsf(d) * kL2E);
  bool up = s > mx;
  sm = (up ? 1.f : sm) + e * (up ? sm : 1.f);
  mx = fmaxf(mx, s);
}
__device__ __forceinline__ void online_merge(float& M, float& S, float Mo, float So) {
  float d = Mo - M;
  float e = fexp2(-fabsf(d) * kL2E);
  bool up = Mo > M;
  S = (up ? So : S) + e * (up ? S : So);
  M = fmaxf(M, Mo);
}
__device__ __forceinline__ u32 pkhalves(u32 a, u32 b) {
#if __has_builtin(__builtin_amdgcn_perm)
  return __builtin_amdgcn_perm(b, a, 0x07060302u);
#else
  return (a >> 16) | (b & 0xffff0000u);
#endif
}
__device__ __forceinline__ void splitpair(float a, float b, u32& hw, u32& lw) {
  u32 ua = __builtin_bit_cast(u32, a), ub = __builtin_bit_cast(u32, b);
  hw = pkhalves(ua, ub);
  float la = a - __builtin_bit_cast(float, ua & 0xffff0000u);
  float lb = b - __builtin_bit_cast(float, ub & 0xffff0000u);
  lw = pkhalves(__builtin_bit_cast(u32, la), __builtin_bit_cast(u32, lb));
}
// s += A*B with split operands: ah*bh + ah*bl + al*bh (drops al*bl, ~2^-16 rel)
__device__ __forceinline__ f32x4 mfma3(bf16x8 ah, bf16x8 al, bf16x8 bh, bf16x8 bl, f32x4 c) {
  c = __builtin_amdgcn_mfma_f32_16x16x32_bf16(ah, bh, c, 0, 0, 0);
  c = __builtin_amdgcn_mfma_f32_16x16x32_bf16(ah, bl, c, 0, 0, 0);
  c = __builtin_amdgcn_mfma_f32_16x16x32_bf16(al, bh, c, 0, 0, 0);
  return c;
}

// ---------------- sentinel (ws too small)
__global__ void sentinel_kernel(float* out, float val, int total) {
  int i = blockIdx.x * 256 + threadIdx.x;
  if (i < total) out[i] = val;
}

// ---------------- split ALL fp32 weight arrays -> bf16 hi/lo arenas (one launch)
__global__ void cvt_all_kernel(const float* __restrict__ s0, const float* __restrict__ s1,
                               const float* __restrict__ s2, const float* __restrict__ s3,
                               u16* h0, u16* l0, u16* h1, u16* l1,
                               u16* h2, u16* l2, u16* h3, u16* l3) {
  int i = blockIdx.x * 256 + threadIdx.x;
  const float* s;
  u16 *dh, *dl;
  int off;
  if (i < 16384) { s = s0; dh = h0; dl = l0; off = i; }
  else if (i < 36864) { s = s1; dh = h1; dl = l1; off = i - 16384; }
  else if (i < 118784) { s = s2; dh = h2; dl = l2; off = i - 36864; }
  else if (i < 200704) { s = s3; dh = h3; dl = l3; off = i - 118784; }
  else return;
  u16 h, l;
  split2(s[off], h, l);
  dh[off] = h;
  dl[off] = l;
}

// ---------------- xh/xl[b][n][c] = split(h[b][c][n])   (setup only)
__global__ __launch_bounds__(256) void prep_kernel(
    const float* __restrict__ h, long hstride, long hoff,
    u16* __restrict__ xh, u16* __restrict__ xl) {
  __shared__ float t[32][33];
  int n0 = blockIdx.x * 32, c0 = blockIdx.y * 32, b = blockIdx.z;
  int tx = threadIdx.x & 31, ty = threadIdx.x >> 5;
#pragma unroll
  for (int i = 0; i < 4; ++i) {
    int c = c0 + ty + i * 8;
    t[ty + i * 8][tx] = h[(size_t)b * hstride + hoff + (size_t)c * kN + n0 + tx];
  }
  __syncthreads();
#pragma unroll
  for (int i = 0; i < 4; ++i) {
    int n = n0 + ty + i * 8, c = c0 + tx;
    u16 hh, ll;
    split2(t[tx][ty + i * 8], hh, ll);
    size_t idx = ((size_t)b * kN + n) * kC + c;
    xh[idx] = hh;
    xl[idx] = ll;
  }
}

// ---------------- QV GEMM (unchanged)
__global__ __launch_bounds__(320) void qv_kernel(
    const u16* __restrict__ xh, const u16* __restrict__ xl,
    const u16* __restrict__ wqkh, const u16* __restrict__ wqkl,
    const u16* __restrict__ wvh, const u16* __restrict__ wvl,
    const float* __restrict__ bv,
    u16* __restrict__ Qh, u16* __restrict__ Ql,
    u16* __restrict__ Vph, u16* __restrict__ Vpl) {
  __shared__ float vt[4][2][16][17];
  int wave = threadIdx.x >> 6, lane = threadIdx.x & 63;
  int b = blockIdx.y;
  int n0 = blockIdx.x * 16;
  int col = lane & 15, g = lane >> 4;
  f32x4 acc[2] = {};
  const u16* xrh = xh + ((size_t)b * kN + n0 + col) * kC + g * 8;
  const u16* xrl = xl + ((size_t)b * kN + n0 + col) * kC + g * 8;
#pragma unroll
  for (int kk = 0; kk < 4; ++kk) {
    bf16x8 bh = *(const bf16x8*)(xrh + kk * 32);
    bf16x8 bl = *(const bf16x8*)(xrl + kk * 32);
#pragma unroll
    for (int i = 0; i < 2; ++i) {
      int ot = wave * 2 + i;
      size_t wi = (ot < 2) ? ((size_t)(ot * 16 + col) * kC) : ((size_t)((ot - 2) * 16 + col) * kC);
      const u16* wsh = (ot < 2) ? (wqkh + wi) : (wvh + wi);
      const u16* wsl = (ot < 2) ? (wqkl + wi) : (wvl + wi);
      bf16x8 ah = *(const bf16x8*)(wsh + kk * 32 + g * 8);
      bf16x8 al = *(const bf16x8*)(wsl + kk * 32 + g * 8);
      acc[i] = mfma3(ah, al, bh, bl, acc[i]);
    }
  }
  if (wave > 0) {
#pragma unroll
    for (int i = 0; i < 2; ++i) {
      int ct = wave * 2 + i - 2;
#pragma unroll
      for (int r = 0; r < 4; ++r)
        vt[wave - 1][i][4 * g + r][col] = acc[i][r] + bv[ct * 16 + 4 * g + r];
    }
  }
  __syncthreads();
  if (wave == 0) {
#pragma unroll
    for (int i = 0; i < 2; ++i) {
#pragma unroll
      for (int r = 0; r < 4; ++r) {
        int d = i * 16 + 4 * g + r;
        u16 hh, ll;
        split2(acc[i][r], hh, ll);
        size_t idx = ((size_t)b * kN + n0 + col) * kD + d;
        Qh[idx] = hh;
        Ql[idx] = ll;
      }
    }
  } else {
    int nt = n0 >> 5, p = (n0 >> 4) & 1;
#pragma unroll
    for (int i = 0; i < 2; ++i) {
      int ct = wave * 2 + i - 2;
      bf16x4 vh4, vl4;
#pragma unroll
      for (int j = 0; j < 4; ++j) {
        float v = vt[wave - 1][i][col][4 * g + j];
        u16 hh, ll;
        split2(v, hh, ll);
        vh4[j] = (short)hh;
        vl4[j] = (short)ll;
      }
      size_t base = ((((size_t)b * (kN / 32) + nt) * 8 + ct) * 64 + lane) * 8 + p * 4;
      *(bf16x4*)(Vph + base) = vh4;
      *(bf16x4*)(Vpl + base) = vl4;
    }
  }
}

// ---------------- pass1 v4 (unchanged)
__global__ __launch_bounds__(256) void pass1_kernel(
    const u16* __restrict__ Qh, const u16* __restrict__ Ql,
    float* __restrict__ rme) {
  __shared__ float mxs[4][32], sms[4][32];
  int wave = threadIdx.x >> 6, lane = threadIdx.x & 63;
  int b = blockIdx.y;
  int n0 = blockIdx.x * 32;
  int col = lane & 15, g = lane >> 4;
  const u16* qbh = Qh + (size_t)b * kN * kD;
  const u16* qbl = Ql + (size_t)b * kN * kD;
  bf16x8 ah0 = *(const bf16x8*)(qbh + (size_t)(n0 + col) * kD + g * 8);
  bf16x8 al0 = *(const bf16x8*)(qbl + (size_t)(n0 + col) * kD + g * 8);
  bf16x8 ah1 = *(const bf16x8*)(qbh + (size_t)(n0 + 16 + col) * kD + g * 8);
  bf16x8 al1 = *(const bf16x8*)(qbl + (size_t)(n0 + 16 + col) * kD + g * 8);
  float mx[8], sm[8];
#pragma unroll
  for (int r = 0; r < 8; ++r) { mx[r] = -3.0e38f; sm[r] = 0.f; }
#pragma unroll 1
  for (int m0 = wave * 16; m0 < kN; m0 += 64) {
    bf16x8 bh = *(const bf16x8*)(qbh + (size_t)(m0 + col) * kD + g * 8);
    bf16x8 bl = *(const bf16x8*)(qbl + (size_t)(m0 + col) * kD + g * 8);
    f32x4 s0 = {}, s1 = {};
    s0 = mfma3(ah0, al0, bh, bl, s0);
    s1 = mfma3(ah1, al1, bh, bl, s1);
#pragma unroll
    for (int r = 0; r < 4; ++r) {
      online_upd(mx[r], sm[r], s0[r]);
      online_upd(mx[r + 4], sm[r + 4], s1[r]);
    }
  }
#pragma unroll
  for (int o = 1; o < 16; o <<= 1) {
#pragma unroll
    for (int r = 0; r < 8; ++r) {
      float Mo = __shfl_xor(mx[r], o, 64);
      float So = __shfl_xor(sm[r], o, 64);
      online_merge(mx[r], sm[r], Mo, So);
    }
  }
  if (col == 0) {
#pragma unroll
    for (int r = 0; r < 4; ++r) {
      mxs[wave][4 * g + r] = mx[r];
      sms[wave][4 * g + r] = sm[r];
      mxs[wave][16 + 4 * g + r] = mx[r + 4];
      sms[wave][16 + 4 * g + r] = sm[r + 4];
    }
  }
  __syncthreads();
  if (threadIdx.x < 32) {
    int t = threadIdx.x;
    float M = mxs[0][t], S = sms[0][t];
#pragma unroll
    for (int w = 1; w < 4; ++w) online_merge(M, S, mxs[w][t], sms[w][t]);
    rme[(size_t)b * kN + n0 + t] = M * kL2E + flog2(S);
  }
}

// ---------------- pass2 v11: attention + FUSED T-conv + BN partials.
// Block owns m-32 rows; yt kept in LDS (stride-136 pad: b128 reads at bank floor);
// after phases A/B each wave runs the tconv GEMM for 2 c-tiles x 2 n-halves.
__global__ __launch_bounds__(256) void pass2_kernel(
    const u16* __restrict__ Qh, const u16* __restrict__ Ql,
    const u16* __restrict__ Vph, const u16* __restrict__ Vpl,
    const float* __restrict__ rme,
    const u16* __restrict__ xh, const u16* __restrict__ xl,
    const u16* __restrict__ twh, const u16* __restrict__ twl,
    const float* __restrict__ tbias,
    float* __restrict__ u, long ustride, long uoff,
    float* __restrict__ part) {
  __shared__ f32x4 accs[4][8][64];
  __shared__ float csl[2][4][16];
  __shared__ u16 yhl[2][32][136];  // [hi/lo][row][c], +8 pad per row
  int wave = threadIdx.x >> 6, lane = threadIdx.x & 63;
  int b = blockIdx.y;
  int m0 = blockIdx.x * 32;
  int col = lane & 15, g = lane >> 4;
  const u16* qbh = Qh + (size_t)b * kN * kD;
  const u16* qbl = Ql + (size_t)b * kN * kD;
  const float* rmb = rme + (size_t)b * kN;
  bf16x8 bmh0 = *(const bf16x8*)(qbh + (size_t)(m0 + col) * kD + g * 8);
  bf16x8 bml0 = *(const bf16x8*)(qbl + (size_t)(m0 + col) * kD + g * 8);
  bf16x8 bmh1 = *(const bf16x8*)(qbh + (size_t)(m0 + 16 + col) * kD + g * 8);
  bf16x8 bml1 = *(const bf16x8*)(qbl + (size_t)(m0 + 16 + col) * kD + g * 8);
  const u16* vbh = Vph + (size_t)b * (kN / 32) * 4096;
  const u16* vbl = Vpl + (size_t)b * (kN / 32) * 4096;
  f32x4 accA[8] = {}, accB[8] = {};
  float csA = 0.f, csB = 0.f;
#pragma unroll 1
  for (int nn = wave * 32; nn < kN; nn += 128) {
    bf16x8 ah0 = *(const bf16x8*)(qbh + (size_t)(nn + col) * kD + g * 8);
    bf16x8 al0 = *(const bf16x8*)(qbl + (size_t)(nn + col) * kD + g * 8);
    bf16x8 ah1 = *(const bf16x8*)(qbh + (size_t)(nn + 16 + col) * kD + g * 8);
    bf16x8 al1 = *(const bf16x8*)(qbl + (size_t)(nn + 16 + col) * kD + g * 8);
    f32x4 sA0 = {}, sA1 = {}, sB0 = {}, sB1 = {};
    sA0 = mfma3(ah0, al0, bmh0, bml0, sA0);
    sA1 = mfma3(ah1, al1, bmh0, bml0, sA1);
    sB0 = mfma3(ah0, al0, bmh1, bml1, sB0);
    sB1 = mfma3(ah1, al1, bmh1, bml1, sB1);
    float pA[8], pB[8];
#pragma unroll
    for (int r = 0; r < 4; ++r) {
      float e0 = rmb[nn + 4 * g + r];
      float e1 = rmb[nn + 16 + 4 * g + r];
      pA[r] = fexp2(sA0[r] * kL2E - e0);
      pA[r + 4] = fexp2(sA1[r] * kL2E - e1);
      pB[r] = fexp2(sB0[r] * kL2E - e0);
      pB[r + 4] = fexp2(sB1[r] * kL2E - e1);
      csA += pA[r] + pA[r + 4];
      csB += pB[r] + pB[r + 4];
    }
    u32x4 Ahw, Alw, Bhw, Blw;
#pragma unroll
    for (int k2 = 0; k2 < 4; ++k2) {
      u32 h0, l0, h1, l1;
      splitpair(pA[2 * k2], pA[2 * k2 + 1], h0, l0);
      splitpair(pB[2 * k2], pB[2 * k2 + 1], h1, l1);
      Ahw[k2] = h0; Alw[k2] = l0;
      Bhw[k2] = h1; Blw[k2] = l1;
    }
    bf16x8 bAh = __builtin_bit_cast(bf16x8, Ahw);
    bf16x8 bAl = __builtin_bit_cast(bf16x8, Alw);
    bf16x8 bBh = __builtin_bit_cast(bf16x8, Bhw);
    bf16x8 bBl = __builtin_bit_cast(bf16x8, Blw);
    size_t vtile = (size_t)(nn >> 5) * 4096;
#pragma unroll
    for (int ct = 0; ct < 8; ++ct) {
      size_t off = vtile + ((size_t)ct * 64 + lane) * 8;
      bf16x8 a8h = *(const bf16x8*)(vbh + off);
      bf16x8 a8l = *(const bf16x8*)(vbl + off);
      accA[ct] = mfma3(a8h, a8l, bAh, bAl, accA[ct]);
      accB[ct] = mfma3(a8h, a8l, bBh, bBl, accB[ct]);
    }
  }
  csA += __shfl_xor(csA, 16, 64);
  csA += __shfl_xor(csA, 32, 64);
  csB += __shfl_xor(csB, 16, 64);
  csB += __shfl_xor(csB, 32, 64);
  if (lane < 16) {
    csl[0][wave][lane] = csA;
    csl[1][wave][lane] = csB;
  }
  // ---- phase A: combine + split y -> LDS rows 0..15 (row = col)
#pragma unroll
  for (int ct = 0; ct < 8; ++ct) accs[wave][ct][lane] = accA[ct];
  __syncthreads();
  {
    float inv = 1.0f / (1e-9f + csl[0][0][col] + csl[0][1][col] + csl[0][2][col] + csl[0][3][col]);
    const u16* xrh = xh + ((size_t)b * kN + m0 + col) * kC;
    const u16* xrl = xl + ((size_t)b * kN + m0 + col) * kC;
#pragma unroll
    for (int i = 0; i < 2; ++i) {
      int ct = wave * 2 + i;
      f32x4 a = accs[0][ct][lane];
      a += accs[1][ct][lane];
      a += accs[2][ct][lane];
      a += accs[3][ct][lane];
      bf16x4 xvh = *(const bf16x4*)(xrh + ct * 16 + 4 * g);
      bf16x4 xvl = *(const bf16x4*)(xrl + ct * 16 + 4 * g);
      bf16x4 yh4, yl4;
#pragma unroll
      for (int r = 0; r < 4; ++r) {
        float xv = bf2f((u16)xvh[r]) + bf2f((u16)xvl[r]);
        float y = xv - a[r] * inv;
        u16 hh, ll;
        split2(y, hh, ll);
        yh4[r] = (short)hh;
        yl4[r] = (short)ll;
      }
      *(bf16x4*)&yhl[0][col][ct * 16 + 4 * g] = yh4;
      *(bf16x4*)&yhl[1][col][ct * 16 + 4 * g] = yl4;
    }
  }
  __syncthreads();
  // ---- phase B: combine + split y -> LDS rows 16..31
#pragma unroll
  for (int ct = 0; ct < 8; ++ct) accs[wave][ct][lane] = accB[ct];
  __syncthreads();
  {
    float inv = 1.0f / (1e-9f + csl[1][0][col] + csl[1][1][col] + csl[1][2][col] + csl[1][3][col]);
    const u16* xrh = xh + ((size_t)b * kN + m0 + 16 + col) * kC;
    const u16* xrl = xl + ((size_t)b * kN + m0 + 16 + col) * kC;
#pragma unroll
    for (int i = 0; i < 2; ++i) {
      int ct = wave * 2 + i;
      f32x4 a = accs[0][ct][lane];
      a += accs[1][ct][lane];
      a += accs[2][ct][lane];
      a += accs[3][ct][lane];
      bf16x4 xvh = *(const bf16x4*)(xrh + ct * 16 + 4 * g);
      bf16x4 xvl = *(const bf16x4*)(xrl + ct * 16 + 4 * g);
      bf16x4 yh4, yl4;
#pragma unroll
      for (int r = 0; r < 4; ++r) {
        float xv = bf2f((u16)xvh[r]) + bf2f((u16)xvl[r]);
        float y = xv - a[r] * inv;
        u16 hh, ll;
        split2(y, hh, ll);
        yh4[r] = (short)hh;
        yl4[r] = (short)ll;
      }
      *(bf16x4*)&yhl[0][16 + col][ct * 16 + 4 * g] = yh4;
      *(bf16x4*)&yhl[1][16 + col][ct * 16 + 4 * g] = yl4;
    }
  }
  __syncthreads();
  // ---- fused T-conv: u[c][m0+h*16+col] = wt[c] . y[row] (+bias), + BN partials
  f32x4 tacc[2][2] = {};  // [i][h]
#pragma unroll
  for (int kk = 0; kk < 4; ++kk) {
#pragma unroll
    for (int h = 0; h < 2; ++h) {
      bf16x8 byh = *(const bf16x8*)&yhl[0][h * 16 + col][kk * 32 + g * 8];
      bf16x8 byl = *(const bf16x8*)&yhl[1][h * 16 + col][kk * 32 + g * 8];
#pragma unroll
      for (int i = 0; i < 2; ++i) {
        int ot = wave * 2 + i;
        bf16x8 ahw = *(const bf16x8*)(twh + (size_t)(ot * 16 + col) * kC + kk * 32 + g * 8);
        bf16x8 alw = *(const bf16x8*)(twl + (size_t)(ot * 16 + col) * kC + kk * 32 + g * 8);
        tacc[i][h] = mfma3(ahw, alw, byh, byl, tacc[i][h]);
      }
    }
  }
  int bid = b * (kN / 32) + (m0 >> 5);
#pragma unroll
  for (int i = 0; i < 2; ++i) {
    int ot = wave * 2 + i;
#pragma unroll
    for (int r = 0; r < 4; ++r) {
      int c = ot * 16 + 4 * g + r;
      float sps = 0.f, spq = 0.f;
#pragma unroll
      for (int h = 0; h < 2; ++h) {
        float v = tacc[i][h][r] + tbias[c];
        u[(size_t)b * ustride + uoff + (size_t)c * kN + m0 + h * 16 + col] = v;
        float s = v, q = v * v;
#pragma unroll
        for (int o = 1; o < 16; o <<= 1) {
          s += __shfl_xor(s, o, 64);
          q += __shfl_xor(q, o, 64);
        }
        sps += s;
        spq += q;
      }
      if (col == 0) {
        part[((size_t)bid * kC + c) * 2 + 0] = sps;
        part[((size_t)bid * kC + c) * 2 + 1] = spq;
      }
    }
  }
}

// ---------------- conv GEMM + fused BN partial sums (setup path only)
__global__ __launch_bounds__(256) void tconv_kernel(
    const u16* __restrict__ inh, const u16* __restrict__ inl,
    const u16* __restrict__ wh, const u16* __restrict__ wl,
    const float* __restrict__ bias, float* __restrict__ u,
    long ustride, long uoff, float* __restrict__ part) {
  int wave = threadIdx.x >> 6, lane = threadIdx.x & 63;
  int b = blockIdx.y;
  int n0 = blockIdx.x * 16;
  int col = lane & 15, g = lane >> 4;
  f32x4 acc[2] = {};
  const u16* xrh = inh + ((size_t)b * kN + n0 + col) * kC + g * 8;
  const u16* xrl = inl + ((size_t)b * kN + n0 + col) * kC + g * 8;
#pragma unroll
  for (int kk = 0; kk < 4; ++kk) {
    bf16x8 bh = *(const bf16x8*)(xrh + kk * 32);
    bf16x8 bl = *(const bf16x8*)(xrl + kk * 32);
#pragma unroll
    for (int i = 0; i < 2; ++i) {
      int ot = wave * 2 + i;
      bf16x8 ah = *(const bf16x8*)(wh + (size_t)(ot * 16 + col) * kC + kk * 32 + g * 8);
      bf16x8 al = *(const bf16x8*)(wl + (size_t)(ot * 16 + col) * kC + kk * 32 + g * 8);
      acc[i] = mfma3(ah, al, bh, bl, acc[i]);
    }
  }
  int bid = blockIdx.y * (kN / 16) + blockIdx.x;
#pragma unroll
  for (int i = 0; i < 2; ++i) {
    int ot = wave * 2 + i;
#pragma unroll
    for (int r = 0; r < 4; ++r) {
      int c = ot * 16 + 4 * g + r;
      float v = acc[i][r] + (bias ? bias[c] : 0.f);
      u[(size_t)b * ustride + uoff + (size_t)c * kN + n0 + col] = v;
      float s = v, q = v * v;
#pragma unroll
      for (int o = 1; o < 16; o <<= 1) {
        s += __shfl_xor(s, o, 64);
        q += __shfl_xor(q, o, 64);
      }
      if (col == 0) {
        part[((size_t)bid * kC + c) * 2 + 0] = s;
        part[((size_t)bid * kC + c) * 2 + 1] = q;
      }
    }
  }
}

// ---------------- BN finalize: reduce cnt fp32 partials/channel in fp64
__global__ __launch_bounds__(256) void bn_fin_kernel(const float* __restrict__ part,
                                                     float* __restrict__ stat, int cnt) {
  int c = blockIdx.x;  // 128 blocks
  __shared__ double rs[4], rss[4];
  double s = 0.0, ss = 0.0;
  for (int k = threadIdx.x; k < cnt; k += 256) {
    s += (double)part[((size_t)k * kC + c) * 2 + 0];
    ss += (double)part[((size_t)k * kC + c) * 2 + 1];
  }
#pragma unroll
  for (int o = 1; o < 64; o <<= 1) {
    s += __shfl_xor(s, o, 64);
    ss += __shfl_xor(ss, o, 64);
  }
  int wid = threadIdx.x >> 6, lane = threadIdx.x & 63;
  if (lane == 0) { rs[wid] = s; rss[wid] = ss; }
  __syncthreads();
  if (threadIdx.x == 0) {
    double S = rs[0] + rs[1] + rs[2] + rs[3];
    double SS = rss[0] + rss[1] + rss[2] + rss[3];
    double mean = S / (double)(kB * kN);
    double var = SS / (double)(kB * kN) - mean * mean;
    if (var < 0.0) var = 0.0;
    stat[c] = (float)mean;
    stat[kC + c] = rsqrtf((float)var + 1e-5f);
  }
}

// ---------------- fused bn_final + next-layer prep (unchanged)
__global__ __launch_bounds__(256) void bnprep_kernel(
    const float* __restrict__ u, long ustride, long uoff,
    const float* __restrict__ stat,
    const float* __restrict__ g, const float* __restrict__ bb,
    const float* __restrict__ h, long hstride, long hoff, int use_res,
    const float* __restrict__ xyz, const float* __restrict__ pw,
    const float* __restrict__ pb,
    float* __restrict__ out, long ostride, long ooff,
    u16* __restrict__ xh, u16* __restrict__ xl) {
  __shared__ float t[32][33];
  int n0 = blockIdx.x * 32, c0 = blockIdx.y * 32, b = blockIdx.z;
  int tx = threadIdx.x & 31, ty = threadIdx.x >> 5;
  const float* xp = xyz + ((size_t)b * kN + n0 + tx) * 3;
  float xv0 = xp[0], xv1 = xp[1], xv2 = xp[2];
#pragma unroll
  for (int i = 0; i < 4; ++i) {
    int c = c0 + ty + i * 8;
    float e = pw[c * 3 + 0] * xv0 + pw[c * 3 + 1] * xv1 + pw[c * 3 + 2] * xv2 + pb[c];
    float y = (u[(size_t)b * ustride + uoff + (size_t)c * kN + n0 + tx] - stat[c]) *
                  stat[kC + c] * g[c] + bb[c];
    y = fmaxf(y, 0.f);
    if (use_res) y += h[(size_t)b * hstride + hoff + (size_t)c * kN + n0 + tx] + e;
    out[(size_t)b * ostride + ooff + (size_t)c * kN + n0 + tx] = y;
    t[ty + i * 8][tx] = y + e;
  }
  __syncthreads();
#pragma unroll
  for (int i = 0; i < 4; ++i) {
    int n = n0 + ty + i * 8, c = c0 + tx;
    u16 hh, ll;
    split2(t[tx][ty + i * 8], hh, ll);
    size_t idx = ((size_t)b * kN + n) * kC + c;
    xh[idx] = hh;
    xl[idx] = ll;
  }
}

extern "C" void kernel_launch(void* const* d_in, const int* in_sizes, int n_in,
                              void* d_out, int out_size, void* d_ws, size_t ws_size,
                              hipStream_t stream) {
  const float* x = (const float*)d_in[0];
  const float* xyz = (const float*)d_in[1];
  const float* conv1_w = (const float*)d_in[2];
  const float* bn1_g = (const float*)d_in[3];
  const float* bn1_b = (const float*)d_in[4];
  const float* pos_w = (const float*)d_in[5];
  const float* pos_b = (const float*)d_in[6];
  const float* sa_wqk = (const float*)d_in[7];
  const float* sa_wv = (const float*)d_in[8];
  const float* sa_bv = (const float*)d_in[9];
  const float* sa_wt = (const float*)d_in[10];
  const float* sa_bt = (const float*)d_in[11];
  const float* sa_bng = (const float*)d_in[12];
  const float* sa_bnb = (const float*)d_in[13];
  float* out = (float*)d_out;
  char* ws = (char*)d_ws;
  const size_t MB = (size_t)1 << 20;

  const size_t NEED = 28 * MB;
  if (ws_size < NEED) {
    float val = 100.0f + (float)(ws_size >> 20);
    sentinel_kernel<<<dim3((out_size + 255) / 256), dim3(256), 0, stream>>>(out, val, out_size);
    return;
  }

  u16* xh = (u16*)(ws);                  // [0,4MB)
  u16* xl = (u16*)(ws + 4 * MB);         // [4,8MB)
  // [8,16MB) free (yt eliminated)
  u16* Vph = (u16*)(ws + 16 * MB);       // [16,20MB)
  u16* Vpl = (u16*)(ws + 20 * MB);       // [20,24MB)
  u16* Qh = (u16*)(ws + 24 * MB);        // [24,25MB)
  u16* Ql = (u16*)(ws + 25 * MB);        // [25,26MB)
  u16* wa = (u16*)(ws + 26 * MB);        // weight split arena
  size_t woff = 0;
  u16* c1h = wa + woff; woff += 16384;
  u16* c1l = wa + woff; woff += 16384;
  u16* qkh = wa + woff; woff += 5 * 32 * 128;
  u16* qkl = wa + woff; woff += 5 * 32 * 128;
  u16* wvh = wa + woff; woff += 5 * 128 * 128;
  u16* wvl = wa + woff; woff += 5 * 128 * 128;
  u16* wth = wa + woff; woff += 5 * 128 * 128;
  u16* wtl = wa + woff; woff += 5 * 128 * 128;
  float* stat = (float*)(ws + 26 * MB + 851968);
  // part (1MB) aliases rme (64KB): rme dead after pass2's QK use; part written after
  float* rme = (float*)(ws + 27 * MB);
  float* part = (float*)(ws + 27 * MB + 65536);  // separate from rme (rme still read in pass2)

  dim3 blk(256);

  cvt_all_kernel<<<dim3(784), blk, 0, stream>>>(
      conv1_w, sa_wqk, sa_wv, sa_wt, c1h, c1l, qkh, qkl, wvh, wvl, wth, wtl);

  const long sbo = (long)kCO * kN;
  const long slice = (long)kC * kN;
  const long h0off = 4 * slice;

  // ---- setup: conv1 + BN + relu -> h0
  prep_kernel<<<dim3(kN / 32, kC / 32, kB), blk, 0, stream>>>(x, slice, 0, xh, xl);
  tconv_kernel<<<dim3(kN / 16, kB), blk, 0, stream>>>(
      xh, xl, c1h, c1l, nullptr, out, sbo, 0, part);
  bn_fin_kernel<<<dim3(kC), blk, 0, stream>>>(part, stat, 1024);
  bnprep_kernel<<<dim3(kN / 32, kC / 32, kB), blk, 0, stream>>>(
      out, sbo, 0, stat, bn1_g, bn1_b, nullptr, 0, 0, 0, xyz, pos_w, pos_b,
      out, sbo, h0off, xh, xl);

  long hoff = h0off;
  for (int i = 0; i < kL; ++i) {
    long uoff = (long)i * slice;
    qv_kernel<<<dim3(kN / 16, kB), dim3(320), 0, stream>>>(
        xh, xl, qkh + (size_t)i * kD * kC, qkl + (size_t)i * kD * kC,
        wvh + (size_t)i * kC * kC, wvl + (size_t)i * kC * kC,
        sa_bv + (size_t)i * kC, Qh, Ql, Vph, Vpl);
    pass1_kernel<<<dim3(kN / 32, kB), blk, 0, stream>>>(Qh, Ql, rme);
    pass2_kernel<<<dim3(kN / 32, kB), blk, 0, stream>>>(
        Qh, Ql, Vph, Vpl, rme, xh, xl,
        wth + (size_t)i * kC * kC, wtl + (size_t)i * kC * kC,
        sa_bt + (size_t)i * kC, out, sbo, uoff, part);
    bn_fin_kernel<<<dim3(kC), blk, 0, stream>>>(part, stat, 512);
    bnprep_kernel<<<dim3(kN / 32, kC / 32, kB), blk, 0, stream>>>(
        out, sbo, uoff, stat, sa_bng + (size_t)i * kC, sa_bnb + (size_t)i * kC,
        out, sbo, hoff, 1, xyz, pos_w, pos_b, out, sbo, uoff, xh, xl);
    hoff = uoff;
  }
}